// Round 15
// baseline (3123.183 us; speedup 1.0000x reference)
//
#include <hip/hip_runtime.h>

// GMAN pipeline, fully fused, MFMA edition. support = I -> per-block token GEMMs.
// B=64, P=Q=12, N=1024, D=64. Output [B,Q,N] fp32.
//
// R26 = R25 resubmitted verbatim (R25's bench died to container-acquisition
// infra failure, same signature as R13/R18; both ran fine on resubmit).
// R25 = TOKEN-PARTITIONED waves: zero barriers in the p-loop.
// Insight: support = I means tokens NEVER interact. The col-partitioned
// scheme needed 5 block-wide barriers/p-step only because each wave read all
// tokens' rows. Re-partition: wave w owns tokens [16w,16w+16) x all 64 dims.
//  - XE/RS/S1/S2 become 4KB per-wave PRIVATE LDS scratch; every dependency
//    (xe->gru1, rs->cand, update->next step) is wave-internal (in-order DS
//    pipe + compiler lgkmcnt). ONE barrier total (FRX staging).
//  - Each wave loops ns=0..3 over all weight-frag slices (B x4/wave); the 4
//    waves/block share the same <=24KB per-phase window -> L1 absorbs the
//    redundancy; L2 holds the 224KB table as before. MFMA/wave unchanged
//    (312/p-step); A-frag reads drop 4x (one M-tile reused across ns).
//  - Biases folded into acc-init (no resident bias regs).
//  - D-ownership is step-stable: scalar phases touch lane-owned addresses.
//  - SWZP 16-token swizzle keeps b128 reads ~2-way (free).
// Tripwires: WRITE ~126MB flat (spill); FETCH >1.5GB = L1 didn't absorb the
// ns-redundancy -> revert R24.

#define NB 1024

typedef float f32x4 __attribute__((ext_vector_type(4)));
typedef __bf16 bf16x8 __attribute__((ext_vector_type(8)));
typedef int i32x4 __attribute__((ext_vector_type(4)));
typedef unsigned int u32;
typedef unsigned short u16;

#define MFMA(a, b, c) __builtin_amdgcn_mfma_f32_16x16x32_bf16(a, b, c, 0, 0, 0)

__device__ __forceinline__ float fexp(float x) {
    return __builtin_amdgcn_exp2f(x * 1.44269504088896341f);
}
__device__ __forceinline__ float fsigmoid(float x) {
    return __builtin_amdgcn_rcpf(1.0f + fexp(-x));
}
__device__ __forceinline__ float ftanh(float x) {
    return 1.0f - 2.0f * __builtin_amdgcn_rcpf(1.0f + fexp(2.0f * x));
}

// pack fp32 -> {bf16 hi | bf16 lo} in one dword (truncation split)
__device__ __forceinline__ u32 packf(float v) {
    u32 u = __builtin_bit_cast(u32, v);
    u32 hb = u & 0xFFFF0000u;
    float lo = v - __builtin_bit_cast(float, hb);
    return hb | (__builtin_bit_cast(u32, lo) >> 16);
}
__device__ __forceinline__ float unpackf(u32 u) {
    return __builtin_bit_cast(float, u & 0xFFFF0000u)
         + __builtin_bit_cast(float, u << 16);
}

__device__ __forceinline__ bf16x8 ldfrag(const u16* p) {
    i32x4 t = *(const i32x4*)p;
    return __builtin_bit_cast(bf16x8, t);
}
__device__ __forceinline__ bf16x8 ldfragL(const u32* p) {
    i32x4 t = *(const i32x4*)p;
    return __builtin_bit_cast(bf16x8, t);
}
__device__ __forceinline__ void split8(f32x4 a0, f32x4 a1, bf16x8& hi, bf16x8& lo) {
    #pragma unroll
    for (int i = 0; i < 4; i++) {
        __bf16 h0 = (__bf16)a0[i]; hi[i] = h0;     lo[i] = (__bf16)(a0[i] - (float)h0);
        __bf16 h1 = (__bf16)a1[i]; hi[4 + i] = h1; lo[4 + i] = (__bf16)(a1[i] - (float)h1);
    }
}

// private-region swizzle: 16 tokens x 64 packed dwords; xor k bits 2..5 by
// tok bits 0..3 -> b128 windows stay 4-aligned, banks spread ~2-way.
#define SWZP(t) ((((t) & 3) << 2) ^ ((((t) >> 2) & 3) << 4))
#define PAD(t, k) ((t) * 64 + ((k) ^ SWZP(t)))

// read packed A-frag from a private region: row t (0..15), 8 k's from kk.
__device__ __forceinline__ void lda16(const u32* __restrict__ src, int t, int kk,
                                      bf16x8& hi, bf16x8& lo) {
    const int sk = kk ^ SWZP(t);
    i32x4 d0 = *(const i32x4*)(src + t * 64 + sk);
    i32x4 d1 = *(const i32x4*)(src + t * 64 + (sk ^ 4));
    i32x4 h, L;
    h[0] = (int)__builtin_amdgcn_perm((u32)d0[1], (u32)d0[0], 0x07060302u);
    h[1] = (int)__builtin_amdgcn_perm((u32)d0[3], (u32)d0[2], 0x07060302u);
    h[2] = (int)__builtin_amdgcn_perm((u32)d1[1], (u32)d1[0], 0x07060302u);
    h[3] = (int)__builtin_amdgcn_perm((u32)d1[3], (u32)d1[2], 0x07060302u);
    L[0] = (int)__builtin_amdgcn_perm((u32)d0[1], (u32)d0[0], 0x05040100u);
    L[1] = (int)__builtin_amdgcn_perm((u32)d0[3], (u32)d0[2], 0x05040100u);
    L[2] = (int)__builtin_amdgcn_perm((u32)d1[1], (u32)d1[0], 0x05040100u);
    L[3] = (int)__builtin_amdgcn_perm((u32)d1[3], (u32)d1[2], 0x05040100u);
    hi = __builtin_bit_cast(bf16x8, h);
    lo = __builtin_bit_cast(bf16x8, L);
}

// ---------------- ws layout (dwords) ----------------
// 0      FR_G1 [ns][nt][ks][half][lane][8bf16] 16384 dw ; 16384 FR_G2
// 32768  FR_C1 [ns][ks][half][lane][8] 8192 dw ; 40960 FR_C2
// 49152  FR_XE Win2 ; 53248 FR_HD Wo1
// 57344  seB [nb(16)][wtok(4)][lane(64)][16] fp32 (b_in2 folded)
// 122880 teo [768][64] fp32

__device__ __forceinline__ void wsplit(float v, u16* dhi, u16* dlo) {
    __bf16 h = (__bf16)v;
    __bf16 l = (__bf16)(v - (float)h);
    *dhi = __builtin_bit_cast(u16, h);
    *dlo = __builtin_bit_cast(u16, l);
}

// ONE fused prep kernel (R24). Only the se output index changed for the
// token-partitioned consumer: lane (q,c16) of token-wave wt reads
// [(nb*4+wt)*64 + q*16 + c16]*16 + ns*4 + r  for tok = wt*16+4q+r, d = ns*16+c16.
__global__ void prep_all(
    const float* __restrict__ Wg1, const float* __restrict__ Wg2,
    const float* __restrict__ Wc1, const float* __restrict__ Wc2,
    const float* __restrict__ Win2, const float* __restrict__ Wo1,
    const float* __restrict__ SE, const float* __restrict__ Wse1,
    const float* __restrict__ bse1, const float* __restrict__ Wse2,
    const float* __restrict__ bse2, const float* __restrict__ bin2,
    const int* __restrict__ TE, const float* __restrict__ Wte1,
    const float* __restrict__ bte1, const float* __restrict__ Wte2,
    const float* __restrict__ bte2,
    u16* __restrict__ fr, float* __restrict__ seB, float* __restrict__ teo) {
    __shared__ float hsh[4][64];
    const int bid = blockIdx.x, tid = threadIdx.x;
    if (bid < 16) {                       // ---- gates
        int i = bid * 256 + tid;
        int layer = i >> 11, r = i & 2047;
        int w = r >> 9; r &= 511; int nt = r >> 8; r &= 255;
        int ks = r >> 6; int lane = r & 63;
        const float* Wg = layer ? Wg2 : Wg1;
        int n = lane & 15, q = lane >> 4;
        int col = nt ? (64 + w * 16 + n) : (w * 16 + n);
        u16* dst = fr + layer * 32768 + (((w * 2 + nt) * 4 + ks) * 2) * 512 + lane * 8;
        #pragma unroll
        for (int j = 0; j < 8; j++) {
            int k = ks * 32 + q * 8 + j;
            float v = Wg[k * 128 + col] + Wg[(k + 128) * 128 + col];
            wsplit(v, dst + j, dst + 512 + j);
        }
    } else if (bid < 24) {                // ---- cand
        int i = (bid - 16) * 256 + tid;
        int layer = i >> 10, r = i & 1023;
        int w = r >> 8; r &= 255; int ks = r >> 6; int lane = r & 63;
        const float* Wc = layer ? Wc2 : Wc1;
        int n = lane & 15, q = lane >> 4;
        int col = w * 16 + n;
        u16* dst = fr + 65536 + layer * 16384 + ((w * 4 + ks) * 2) * 512 + lane * 8;
        #pragma unroll
        for (int j = 0; j < 8; j++) {
            int k = ks * 32 + q * 8 + j;
            float v = Wc[k * 64 + col] + Wc[(k + 128) * 64 + col];
            wsplit(v, dst + j, dst + 512 + j);
        }
    } else if (bid < 28) {                // ---- small (Win2 / Wo1)
        int i = (bid - 24) * 256 + tid;
        int kind = i >> 9, r = i & 511;
        int w = r >> 7; r &= 127; int ks = r >> 6; int lane = r & 63;
        const float* W = kind ? Wo1 : Win2;
        int n = lane & 15, q = lane >> 4;
        int col = w * 16 + n;
        u16* dst = fr + 98304 + kind * 8192 + ((w * 2 + ks) * 2) * 512 + lane * 8;
        #pragma unroll
        for (int j = 0; j < 8; j++) {
            int k = ks * 32 + q * 8 + j;
            float v = W[k * 64 + col];
            wsplit(v, dst + j, dst + 512 + j);
        }
    } else if (bid < 284) {               // ---- se: 4 rows per block
        int sb = tid >> 6, d = tid & 63;
        int n = (bid - 28) * 4 + sb;
        float acc = bse1[d];
        for (int k = 0; k < 64; k++) acc = fmaf(SE[n * 64 + k], Wse1[k * 64 + d], acc);
        hsh[sb][d] = fmaxf(acc, 0.0f);
        __syncthreads();
        float acc2 = bse2[d];
        for (int k = 0; k < 64; k++) acc2 = fmaf(hsh[sb][k], Wse2[k * 64 + d], acc2);
        int nb = n >> 6, tok = n & 63;
        int wt = tok >> 4, q = (tok >> 2) & 3, r = tok & 3;
        int ns = d >> 4, c16 = d & 15;
        seB[(((nb * 4 + wt) * 64) + q * 16 + c16) * 16 + ns * 4 + r] = acc2 + bin2[d];
    } else {                              // ---- te: 4 rows per block
        int sb = tid >> 6, d = tid & 63;
        int bp = (bid - 284) * 4 + sb;
        int b = bp / 12, p = bp - b * 12;
        int dow = TE[(b * 24 + p) * 2 + 0];
        int tod = TE[(b * 24 + p) * 2 + 1];
        float v = Wte1[dow * 64 + d] + Wte1[(7 + tod) * 64 + d] + bte1[d];
        hsh[sb][d] = fmaxf(v, 0.0f);
        __syncthreads();
        float acc = bte2[d];
        for (int k = 0; k < 64; k++) acc = fmaf(hsh[sb][k], Wte2[k * 64 + d], acc);
        teo[bp * 64 + d] = acc;
    }
}

// full GRU step, token-private edition. Wave owns 16 tokens x 64 dims.
// ns loops over all 4 weight-frag slices. Biases pre-loaded into acc-init.
// All LDS traffic is to this wave's private regions -> NO barriers.
__device__ __forceinline__ void gru_full(
    const u32* __restrict__ XIN, u32* __restrict__ S, u32* __restrict__ RS,
    const u16* __restrict__ frG, const u16* __restrict__ frC,
    const float* __restrict__ bg, const float* __restrict__ bc, int l) {
    const int l15 = l & 15, q = l >> 4;
    f32x4 accR[4], accU[4], accC[4];
    #pragma unroll
    for (int ns = 0; ns < 4; ns++) {
        accR[ns] = (f32x4)(bg[ns * 16 + l15]);
        accU[ns] = (f32x4)(bg[64 + ns * 16 + l15]);
        accC[ns] = (f32x4)(bc[ns * 16 + l15]);
    }
    // phase 1: ks 0..1 (XIN K-half): one A-tile reused across all 4 ns
    #pragma unroll
    for (int ks = 0; ks < 2; ks++) {
        bf16x8 ahi, alo;
        lda16(XIN, l15, ks * 32 + q * 8, ahi, alo);
        #pragma unroll
        for (int ns = 0; ns < 4; ns++) {
            const u16* fg = frG + ns * 8192;
            bf16x8 gRh = ldfrag(fg + (ks * 2 + 0) * 512 + l * 8);
            bf16x8 gRl = ldfrag(fg + (ks * 2 + 1) * 512 + l * 8);
            bf16x8 gUh = ldfrag(fg + (8 + ks * 2 + 0) * 512 + l * 8);
            bf16x8 gUl = ldfrag(fg + (8 + ks * 2 + 1) * 512 + l * 8);
            const u16* fc = frC + ns * 4096;
            bf16x8 bhiC = ldfrag(fc + (ks * 2 + 0) * 512 + l * 8);
            bf16x8 bloC = ldfrag(fc + (ks * 2 + 1) * 512 + l * 8);
            accR[ns] = MFMA(ahi, gRh, accR[ns]);
            accR[ns] = MFMA(alo, gRh, accR[ns]);
            accR[ns] = MFMA(ahi, gRl, accR[ns]);
            accU[ns] = MFMA(ahi, gUh, accU[ns]);
            accU[ns] = MFMA(alo, gUh, accU[ns]);
            accU[ns] = MFMA(ahi, gUl, accU[ns]);
            accC[ns] = MFMA(ahi, bhiC, accC[ns]);
            accC[ns] = MFMA(alo, bhiC, accC[ns]);
            accC[ns] = MFMA(ahi, bloC, accC[ns]);
        }
    }
    // phase 2: ks 2..3 (S K-half): gates only
    #pragma unroll
    for (int ks = 2; ks < 4; ks++) {
        bf16x8 ahi, alo;
        lda16(S, l15, (ks - 2) * 32 + q * 8, ahi, alo);
        #pragma unroll
        for (int ns = 0; ns < 4; ns++) {
            const u16* fg = frG + ns * 8192;
            bf16x8 gRh = ldfrag(fg + (ks * 2 + 0) * 512 + l * 8);
            bf16x8 gRl = ldfrag(fg + (ks * 2 + 1) * 512 + l * 8);
            bf16x8 gUh = ldfrag(fg + (8 + ks * 2 + 0) * 512 + l * 8);
            bf16x8 gUl = ldfrag(fg + (8 + ks * 2 + 1) * 512 + l * 8);
            accR[ns] = MFMA(ahi, gRh, accR[ns]);
            accR[ns] = MFMA(alo, gRh, accR[ns]);
            accR[ns] = MFMA(ahi, gRl, accR[ns]);
            accU[ns] = MFMA(ahi, gUh, accU[ns]);
            accU[ns] = MFMA(alo, gUh, accU[ns]);
            accU[ns] = MFMA(ahi, gUl, accU[ns]);
        }
    }
    // rs = sigmoid(r) * s  (bias already in acc; lane-owned addresses)
    #pragma unroll
    for (int ns = 0; ns < 4; ns++)
        #pragma unroll
        for (int r = 0; r < 4; r++) {
            int a = PAD(4 * q + r, ns * 16 + l15);
            RS[a] = packf(fsigmoid(accR[ns][r]) * unpackf(S[a]));
        }
    // cand ks 2..3 (RS K-half) — same-wave RAW through LDS, no barrier
    #pragma unroll
    for (int ks = 2; ks < 4; ks++) {
        bf16x8 ahi, alo;
        lda16(RS, l15, (ks - 2) * 32 + q * 8, ahi, alo);
        #pragma unroll
        for (int ns = 0; ns < 4; ns++) {
            const u16* fc = frC + ns * 4096;
            bf16x8 bhi = ldfrag(fc + (ks * 2 + 0) * 512 + l * 8);
            bf16x8 blo = ldfrag(fc + (ks * 2 + 1) * 512 + l * 8);
            accC[ns] = MFMA(ahi, bhi, accC[ns]);
            accC[ns] = MFMA(alo, bhi, accC[ns]);
            accC[ns] = MFMA(ahi, blo, accC[ns]);
        }
    }
    // state update (lane-owned addresses)
    #pragma unroll
    for (int ns = 0; ns < 4; ns++)
        #pragma unroll
        for (int r = 0; r < 4; r++) {
            int a = PAD(4 * q + r, ns * 16 + l15);
            float u = fsigmoid(accU[ns][r]);
            float cnd = ftanh(accC[ns][r]);
            float sold = unpackf(S[a]);
            S[a] = packf(u * sold + (1.0f - u) * cnd);
        }
}

__global__ __launch_bounds__(256, 2) void gman_main(
    const float* __restrict__ X, const float* __restrict__ ws,
    const float* __restrict__ Win1, const float* __restrict__ bin1,
    const float* __restrict__ bg1, const float* __restrict__ bc1,
    const float* __restrict__ bg2, const float* __restrict__ bc2,
    const float* __restrict__ bo1, const float* __restrict__ Wo2,
    const float* __restrict__ bo2, float* __restrict__ out) {
    __shared__ u32 XEb[4096], RSb[4096], S1b[4096], S2b[4096];  // 64 KB
    __shared__ u32 FRX[4096];                                   // +16 KB
    // 80 KB; 2 blocks/CU. Per-wave private 1024-dw regions in each buffer.

    const int tid = threadIdx.x;
    const int l = tid & 63;
    const int w = tid >> 6;
    const int uw = __builtin_amdgcn_readfirstlane(w);
    const int l15 = l & 15, q = l >> 4;
    const int b = blockIdx.x >> 4;
    const int nb = blockIdx.x & 15;
    const int n0 = nb << 6;

    u32* XE = XEb + uw * 1024;
    u32* RS = RSb + uw * 1024;
    u32* S1 = S1b + uw * 1024;
    u32* S2 = S2b + uw * 1024;

    const u16* frU = (const u16*)ws;
    const float* seQ = ws + 57344 + (((nb * 4 + uw) * 64) + l) * 16;
    const float* teo = ws + 122880;

    // stage Win2 frag table into LDS (shared, read-only after barrier)
    const u32* frXsrc = (const u32*)ws + 49152;
    #pragma unroll
    for (int i = 0; i < 16; i++) FRX[tid + i * 256] = frXsrc[tid + i * 256];
    // zero own state regions (wave-private, no barrier needed for these)
    #pragma unroll
    for (int i = 0; i < 16; i++) { S1[l + i * 64] = 0u; S2[l + i * 64] = 0u; }
    __syncthreads();   // FRX visible — the ONLY block-wide barrier

    #pragma unroll 1
    for (int p = 0; p < 12; p++) {
        const int bp = b * 12 + p;
        // xe GEMM: A = h1 = relu(x*Win1+bin1) built in regs (own 16 tokens)
        const float xv = X[bp * NB + n0 + uw * 16 + l15];
        f32x4 accX[4];
        #pragma unroll
        for (int ns = 0; ns < 4; ns++) accX[ns] = (f32x4)0.0f;
        #pragma unroll
        for (int ks = 0; ks < 2; ks++) {
            const int k0 = ks * 32 + q * 8;
            f32x4 w1a = *(const f32x4*)(Win1 + k0), w1b = *(const f32x4*)(Win1 + k0 + 4);
            f32x4 b1a = *(const f32x4*)(bin1 + k0), b1b = *(const f32x4*)(bin1 + k0 + 4);
            f32x4 h0, h1v;
            #pragma unroll
            for (int i = 0; i < 4; i++) {
                h0[i]  = fmaxf(fmaf(xv, w1a[i], b1a[i]), 0.0f);
                h1v[i] = fmaxf(fmaf(xv, w1b[i], b1b[i]), 0.0f);
            }
            bf16x8 ahi, alo; split8(h0, h1v, ahi, alo);
            #pragma unroll
            for (int ns = 0; ns < 4; ns++) {
                bf16x8 bhi = ldfragL(FRX + ns * 1024 + (ks * 2 + 0) * 256 + l * 4);
                bf16x8 blo = ldfragL(FRX + ns * 1024 + (ks * 2 + 1) * 256 + l * 4);
                accX[ns] = MFMA(ahi, bhi, accX[ns]);
                accX[ns] = MFMA(alo, bhi, accX[ns]);
                accX[ns] = MFMA(ahi, blo, accX[ns]);
            }
        }
        // epilogue: + se + te, write packed into private XE
        #pragma unroll
        for (int ns = 0; ns < 4; ns++) {
            f32x4 sev = *(const f32x4*)(seQ + ns * 4);
            const float tev = teo[bp * 64 + ns * 16 + l15];
            #pragma unroll
            for (int r = 0; r < 4; r++)
                XE[PAD(4 * q + r, ns * 16 + l15)] = packf(accX[ns][r] + sev[r] + tev);
        }

        gru_full(XE, S1, RS, frU, frU + 65536, bg1, bc1, l);
        gru_full(S1, S2, RS, frU + 32768, frU + 81920, bg2, bc2, l);
    }

    // head: h = relu(S2@Wo1+bo1) via MFMA into private XE, then y GEMV
    f32x4 accH[4];
    #pragma unroll
    for (int ns = 0; ns < 4; ns++) accH[ns] = (f32x4)(bo1[ns * 16 + l15]);
    #pragma unroll
    for (int ks = 0; ks < 2; ks++) {
        bf16x8 ahi, alo;
        lda16(S2, l15, ks * 32 + q * 8, ahi, alo);
        #pragma unroll
        for (int ns = 0; ns < 4; ns++) {
            const u16* fh = frU + 106496 + ns * 2048;
            bf16x8 bhi = ldfrag(fh + (ks * 2 + 0) * 512 + l * 8);
            bf16x8 blo = ldfrag(fh + (ks * 2 + 1) * 512 + l * 8);
            accH[ns] = MFMA(ahi, bhi, accH[ns]);
            accH[ns] = MFMA(alo, bhi, accH[ns]);
            accH[ns] = MFMA(ahi, blo, accH[ns]);
        }
    }
    #pragma unroll
    for (int ns = 0; ns < 4; ns++)
        #pragma unroll
        for (int r = 0; r < 4; r++)
            XE[PAD(4 * q + r, ns * 16 + l15)] = packf(fmaxf(accH[ns][r], 0.0f));
    // y GEMV: lane (l15 = token, q): owns q-cols 3q..3q+2 (wave-internal LDS)
    const int swz = SWZP(l15);
    float y0 = bo2[3 * q + 0], y1 = bo2[3 * q + 1], y2 = bo2[3 * q + 2];
    #pragma unroll
    for (int c4 = 0; c4 < 16; c4++) {
        i32x4 d = *(const i32x4*)(XE + l15 * 64 + ((c4 * 4) ^ swz));
        #pragma unroll
        for (int e = 0; e < 4; e++) {
            float hj = unpackf((u32)d[e]);
            int j = c4 * 4 + e;
            y0 = fmaf(hj, Wo2[j * 12 + 3 * q + 0], y0);
            y1 = fmaf(hj, Wo2[j * 12 + 3 * q + 1], y1);
            y2 = fmaf(hj, Wo2[j * 12 + 3 * q + 2], y2);
        }
    }
    const int tg = n0 + uw * 16 + l15;
    out[(b * 12 + 3 * q + 0) * NB + tg] = y0;
    out[(b * 12 + 3 * q + 1) * NB + tg] = y1;
    out[(b * 12 + 3 * q + 2) * NB + tg] = y2;
}

extern "C" void kernel_launch(void* const* d_in, const int* in_sizes, int n_in,
                              void* d_out, int out_size, void* d_ws, size_t ws_size,
                              hipStream_t stream) {
    const float* X    = (const float*)d_in[0];
    // d_in[1]=ZC, d_in[2]=ZF unused by the reference
    const float* SE   = (const float*)d_in[3];
    const float* Wse1 = (const float*)d_in[4];
    const float* bse1 = (const float*)d_in[5];
    const float* Wse2 = (const float*)d_in[6];
    const float* bse2 = (const float*)d_in[7];
    const float* Wte1 = (const float*)d_in[8];
    const float* bte1 = (const float*)d_in[9];
    const float* Wte2 = (const float*)d_in[10];
    const float* bte2 = (const float*)d_in[11];
    const float* Win1 = (const float*)d_in[12];
    const float* bin1 = (const float*)d_in[13];
    const float* Win2 = (const float*)d_in[14];
    const float* bin2 = (const float*)d_in[15];
    const float* Wg1  = (const float*)d_in[16];
    const float* bg1  = (const float*)d_in[17];
    const float* Wc1  = (const float*)d_in[18];
    const float* bc1  = (const float*)d_in[19];
    const float* Wg2  = (const float*)d_in[20];
    const float* bg2  = (const float*)d_in[21];
    const float* Wc2  = (const float*)d_in[22];
    const float* bc2  = (const float*)d_in[23];
    const float* Wo1  = (const float*)d_in[24];
    const float* bo1  = (const float*)d_in[25];
    const float* Wo2  = (const float*)d_in[26];
    const float* bo2  = (const float*)d_in[27];
    const int*   TE   = (const int*)d_in[28];

    float* ws = (float*)d_ws;                  // 172032 floats = 688 KB
    u16* fr = (u16*)ws;
    float* seB = ws + 57344;
    float* teo = ws + 122880;
    float* out = (float*)d_out;

    prep_all<<<476, 256, 0, stream>>>(Wg1, Wg2, Wc1, Wc2, Win2, Wo1,
                                      SE, Wse1, bse1, Wse2, bse2, bin2,
                                      TE, Wte1, bte1, Wte2, bte2,
                                      fr, seB, teo);
    gman_main<<<1024, 256, 0, stream>>>(X, ws, Win1, bin1, bg1, bc1, bg2, bc2,
                                        bo1, Wo2, bo2, out);
}

// Round 16
// 626.852 us; speedup vs baseline: 4.9823x; 4.9823x over previous
//
#include <hip/hip_runtime.h>

// GMAN pipeline, fully fused, MFMA edition. support = I -> per-block token GEMMs.
// B=64, P=Q=12, N=1024, D=64. Output [B,Q,N] fp32.
//
// R27 = 32-token blocks (2048 blocks x 256 thr), 32 KB LDS: a clean probe of
// the LDS-allocation-granularity hypothesis.
// Evidence trail:
//  - R26 (token-private): CORRECT but 3030us. WRITE 937MB (global B-frag
//    loads hoisted en masse -> ~890dw/thread spill), FETCH 5.4GB (4x frag
//    stream, L1 didn't absorb; scratch churn took L2 hit-rate 72%->43%).
//    LAW: per-wave weight-stream is conserved; partitions that multiply it
//    lose. Token-private CLOSED.
//  - Occupancy ledger: 80KB->2 blocks, 64KB->2, 48KB->~8 waves still.
//    Consistent with ~64KB LDS granules/WG. Probe: 32KB request.
//  - 32-token blocks: per-wave frag stream UNCHANGED (col-slice); accs 48->24
//    regs; MFMA/wave halves; block count doubles. If granule <=32KB: 4-5
//    blocks/CU = 16-20 waves (VGPR 128 admits 4/SIMD).
//  - De-risked: no alias, no soldv, separate RS, packed format, no FRX.
// Verdict metric: OccupancyPercent ~22% = hypothesis dead -> finalize R24;
// >=33% = occupancy finally purchased. FETCH >1.5GB = HBM-bound, revert.

#define NB 1024

typedef float f32x4 __attribute__((ext_vector_type(4)));
typedef __bf16 bf16x8 __attribute__((ext_vector_type(8)));
typedef int i32x4 __attribute__((ext_vector_type(4)));
typedef unsigned int u32;
typedef unsigned short u16;

#define MFMA(a, b, c) __builtin_amdgcn_mfma_f32_16x16x32_bf16(a, b, c, 0, 0, 0)

__device__ __forceinline__ float fexp(float x) {
    return __builtin_amdgcn_exp2f(x * 1.44269504088896341f);
}
__device__ __forceinline__ float fsigmoid(float x) {
    return __builtin_amdgcn_rcpf(1.0f + fexp(-x));
}
__device__ __forceinline__ float ftanh(float x) {
    return 1.0f - 2.0f * __builtin_amdgcn_rcpf(1.0f + fexp(2.0f * x));
}

// pack fp32 -> {bf16 hi | bf16 lo} in one dword (truncation split)
__device__ __forceinline__ u32 packf(float v) {
    u32 u = __builtin_bit_cast(u32, v);
    u32 hb = u & 0xFFFF0000u;
    float lo = v - __builtin_bit_cast(float, hb);
    return hb | (__builtin_bit_cast(u32, lo) >> 16);
}
__device__ __forceinline__ float unpackf(u32 u) {
    return __builtin_bit_cast(float, u & 0xFFFF0000u)
         + __builtin_bit_cast(float, u << 16);
}

__device__ __forceinline__ bf16x8 ldfrag(const u16* p) {
    i32x4 t = *(const i32x4*)p;
    return __builtin_bit_cast(bf16x8, t);
}
__device__ __forceinline__ void split8(f32x4 a0, f32x4 a1, bf16x8& hi, bf16x8& lo) {
    #pragma unroll
    for (int i = 0; i < 4; i++) {
        __bf16 h0 = (__bf16)a0[i]; hi[i] = h0;     lo[i] = (__bf16)(a0[i] - (float)h0);
        __bf16 h1 = (__bf16)a1[i]; hi[4 + i] = h1; lo[4 + i] = (__bf16)(a1[i] - (float)h1);
    }
}

// swizzle: xor k bits 2..4 by t bits; k bits 0-1 intact -> 4-dword windows legal
#define SWZ(t) ((((t) & 3) << 3) ^ ((t) & 4) ^ (((t) & 8) << 1))
#define SW(t, k) ((t) * 64 + ((k) ^ SWZ(t)))

// read packed A-frag: 8 consecutive k from swizzled row m, extract hi/lo via v_perm
__device__ __forceinline__ void lda_packed(const u32* __restrict__ src, int m, int kk,
                                           bf16x8& hi, bf16x8& lo) {
    const int sk = kk ^ SWZ(m);
    i32x4 d0 = *(const i32x4*)(src + m * 64 + sk);
    i32x4 d1 = *(const i32x4*)(src + m * 64 + (sk ^ 4));
    i32x4 h, L;
    h[0] = (int)__builtin_amdgcn_perm((u32)d0[1], (u32)d0[0], 0x07060302u);
    h[1] = (int)__builtin_amdgcn_perm((u32)d0[3], (u32)d0[2], 0x07060302u);
    h[2] = (int)__builtin_amdgcn_perm((u32)d1[1], (u32)d1[0], 0x07060302u);
    h[3] = (int)__builtin_amdgcn_perm((u32)d1[3], (u32)d1[2], 0x07060302u);
    L[0] = (int)__builtin_amdgcn_perm((u32)d0[1], (u32)d0[0], 0x05040100u);
    L[1] = (int)__builtin_amdgcn_perm((u32)d0[3], (u32)d0[2], 0x05040100u);
    L[2] = (int)__builtin_amdgcn_perm((u32)d1[1], (u32)d1[0], 0x05040100u);
    L[3] = (int)__builtin_amdgcn_perm((u32)d1[3], (u32)d1[2], 0x05040100u);
    hi = __builtin_bit_cast(bf16x8, h);
    lo = __builtin_bit_cast(bf16x8, L);
}

// ---------------- ws layout (dwords) ----------------
// 0      FR_G1 [wq][nt][ks][half][lane][8bf16] 16384 dw ; 16384 FR_G2
// 32768  FR_C1 [wq][ks][half][lane][8] 8192 dw ; 40960 FR_C2
// 49152  FR_XE Win2 ; 53248 FR_HD Wo1
// 57344  seB [nbOld(16)][w(4)][lane(64)][16] fp32 (b_in2 folded)
// 122880 teo [768][64] fp32

__device__ __forceinline__ void wsplit(float v, u16* dhi, u16* dlo) {
    __bf16 h = (__bf16)v;
    __bf16 l = (__bf16)(v - (float)h);
    *dhi = __builtin_bit_cast(u16, h);
    *dlo = __builtin_bit_cast(u16, l);
}

// ONE fused prep kernel (R24, unchanged layouts).
__global__ void prep_all(
    const float* __restrict__ Wg1, const float* __restrict__ Wg2,
    const float* __restrict__ Wc1, const float* __restrict__ Wc2,
    const float* __restrict__ Win2, const float* __restrict__ Wo1,
    const float* __restrict__ SE, const float* __restrict__ Wse1,
    const float* __restrict__ bse1, const float* __restrict__ Wse2,
    const float* __restrict__ bse2, const float* __restrict__ bin2,
    const int* __restrict__ TE, const float* __restrict__ Wte1,
    const float* __restrict__ bte1, const float* __restrict__ Wte2,
    const float* __restrict__ bte2,
    u16* __restrict__ fr, float* __restrict__ seB, float* __restrict__ teo) {
    __shared__ float hsh[4][64];
    const int bid = blockIdx.x, tid = threadIdx.x;
    if (bid < 16) {                       // ---- gates
        int i = bid * 256 + tid;
        int layer = i >> 11, r = i & 2047;
        int w = r >> 9; r &= 511; int nt = r >> 8; r &= 255;
        int ks = r >> 6; int lane = r & 63;
        const float* Wg = layer ? Wg2 : Wg1;
        int n = lane & 15, q = lane >> 4;
        int col = nt ? (64 + w * 16 + n) : (w * 16 + n);
        u16* dst = fr + layer * 32768 + (((w * 2 + nt) * 4 + ks) * 2) * 512 + lane * 8;
        #pragma unroll
        for (int j = 0; j < 8; j++) {
            int k = ks * 32 + q * 8 + j;
            float v = Wg[k * 128 + col] + Wg[(k + 128) * 128 + col];
            wsplit(v, dst + j, dst + 512 + j);
        }
    } else if (bid < 24) {                // ---- cand
        int i = (bid - 16) * 256 + tid;
        int layer = i >> 10, r = i & 1023;
        int w = r >> 8; r &= 255; int ks = r >> 6; int lane = r & 63;
        const float* Wc = layer ? Wc2 : Wc1;
        int n = lane & 15, q = lane >> 4;
        int col = w * 16 + n;
        u16* dst = fr + 65536 + layer * 16384 + ((w * 4 + ks) * 2) * 512 + lane * 8;
        #pragma unroll
        for (int j = 0; j < 8; j++) {
            int k = ks * 32 + q * 8 + j;
            float v = Wc[k * 64 + col] + Wc[(k + 128) * 64 + col];
            wsplit(v, dst + j, dst + 512 + j);
        }
    } else if (bid < 28) {                // ---- small (Win2 / Wo1)
        int i = (bid - 24) * 256 + tid;
        int kind = i >> 9, r = i & 511;
        int w = r >> 7; r &= 127; int ks = r >> 6; int lane = r & 63;
        const float* W = kind ? Wo1 : Win2;
        int n = lane & 15, q = lane >> 4;
        int col = w * 16 + n;
        u16* dst = fr + 98304 + kind * 8192 + ((w * 2 + ks) * 2) * 512 + lane * 8;
        #pragma unroll
        for (int j = 0; j < 8; j++) {
            int k = ks * 32 + q * 8 + j;
            float v = W[k * 64 + col];
            wsplit(v, dst + j, dst + 512 + j);
        }
    } else if (bid < 284) {               // ---- se: 4 rows per block
        int sb = tid >> 6, d = tid & 63;
        int n = (bid - 28) * 4 + sb;
        float acc = bse1[d];
        for (int k = 0; k < 64; k++) acc = fmaf(SE[n * 64 + k], Wse1[k * 64 + d], acc);
        hsh[sb][d] = fmaxf(acc, 0.0f);
        __syncthreads();
        float acc2 = bse2[d];
        for (int k = 0; k < 64; k++) acc2 = fmaf(hsh[sb][k], Wse2[k * 64 + d], acc2);
        int nb = n >> 6, tok = n & 63;
        int mt = tok >> 4, q = (tok >> 2) & 3, r = tok & 3;
        int w = d >> 4, n16 = d & 15;
        seB[(((nb * 4 + w) * 64) + q * 16 + n16) * 16 + mt * 4 + r] = acc2 + bin2[d];
    } else {                              // ---- te: 4 rows per block
        int sb = tid >> 6, d = tid & 63;
        int bp = (bid - 284) * 4 + sb;
        int b = bp / 12, p = bp - b * 12;
        int dow = TE[(b * 24 + p) * 2 + 0];
        int tod = TE[(b * 24 + p) * 2 + 1];
        float v = Wte1[dow * 64 + d] + Wte1[(7 + tod) * 64 + d] + bte1[d];
        hsh[sb][d] = fmaxf(v, 0.0f);
        __syncthreads();
        float acc = bte2[d];
        for (int k = 0; k < 64; k++) acc = fmaf(hsh[sb][k], Wte2[k * 64 + d], acc);
        teo[bp * 64 + d] = acc;
    }
}

// full GRU step, 32-token block. Wave owns cols [16w,16w+16) x 32 tokens
// (mt = 0..1). Gate + cand fragments streamed from ws (L2-resident).
__device__ __forceinline__ void gru_full(
    const u32* __restrict__ XIN, u32* __restrict__ S, u32* __restrict__ RS,
    const u16* __restrict__ frG, const u16* __restrict__ frC,
    float bgr, float bgu, float bcc, int l, int col) {
    const int n16 = l & 15, q = l >> 4;
    f32x4 accR[2], accU[2], accC[2];
    #pragma unroll
    for (int mt = 0; mt < 2; mt++) {
        accR[mt] = (f32x4)0.0f; accU[mt] = (f32x4)0.0f; accC[mt] = (f32x4)0.0f;
    }
    // phase 1: ks 0..1 (XIN K-half): one A-frag feeds R+U+C
    #pragma unroll
    for (int ks = 0; ks < 2; ks++) {
        bf16x8 gRh = ldfrag(frG + (ks * 2 + 0) * 512 + l * 8);
        bf16x8 gRl = ldfrag(frG + (ks * 2 + 1) * 512 + l * 8);
        bf16x8 gUh = ldfrag(frG + (8 + ks * 2 + 0) * 512 + l * 8);
        bf16x8 gUl = ldfrag(frG + (8 + ks * 2 + 1) * 512 + l * 8);
        bf16x8 bhiC = ldfrag(frC + (ks * 2 + 0) * 512 + l * 8);
        bf16x8 bloC = ldfrag(frC + (ks * 2 + 1) * 512 + l * 8);
        const int kk = ks * 32 + q * 8;
        #pragma unroll
        for (int mt = 0; mt < 2; mt++) {
            bf16x8 ahi, alo;
            lda_packed(XIN, mt * 16 + n16, kk, ahi, alo);
            accR[mt] = MFMA(ahi, gRh, accR[mt]);
            accR[mt] = MFMA(alo, gRh, accR[mt]);
            accR[mt] = MFMA(ahi, gRl, accR[mt]);
            accU[mt] = MFMA(ahi, gUh, accU[mt]);
            accU[mt] = MFMA(alo, gUh, accU[mt]);
            accU[mt] = MFMA(ahi, gUl, accU[mt]);
            accC[mt] = MFMA(ahi, bhiC, accC[mt]);
            accC[mt] = MFMA(alo, bhiC, accC[mt]);
            accC[mt] = MFMA(ahi, bloC, accC[mt]);
        }
    }
    // phase 2: ks 2..3 (S K-half): gates only
    #pragma unroll
    for (int ks = 2; ks < 4; ks++) {
        bf16x8 gRh = ldfrag(frG + (ks * 2 + 0) * 512 + l * 8);
        bf16x8 gRl = ldfrag(frG + (ks * 2 + 1) * 512 + l * 8);
        bf16x8 gUh = ldfrag(frG + (8 + ks * 2 + 0) * 512 + l * 8);
        bf16x8 gUl = ldfrag(frG + (8 + ks * 2 + 1) * 512 + l * 8);
        const int kk = (ks - 2) * 32 + q * 8;
        #pragma unroll
        for (int mt = 0; mt < 2; mt++) {
            bf16x8 ahi, alo;
            lda_packed(S, mt * 16 + n16, kk, ahi, alo);
            accR[mt] = MFMA(ahi, gRh, accR[mt]);
            accR[mt] = MFMA(alo, gRh, accR[mt]);
            accR[mt] = MFMA(ahi, gRl, accR[mt]);
            accU[mt] = MFMA(ahi, gUh, accU[mt]);
            accU[mt] = MFMA(alo, gUh, accU[mt]);
            accU[mt] = MFMA(ahi, gUl, accU[mt]);
        }
    }
    // rs = sigmoid(r) * s (RS separate buffer -> no barrier needed first)
    #pragma unroll
    for (int mt = 0; mt < 2; mt++)
        #pragma unroll
        for (int r = 0; r < 4; r++) {
            int tok = mt * 16 + q * 4 + r;
            int a = SW(tok, col);
            RS[a] = packf(fsigmoid(accR[mt][r] + bgr) * unpackf(S[a]));
        }
    __syncthreads();   // rs visible
    // cand ks 2..3 (RS K-half)
    #pragma unroll
    for (int ks = 2; ks < 4; ks++) {
        bf16x8 bhi = ldfrag(frC + (ks * 2 + 0) * 512 + l * 8);
        bf16x8 blo = ldfrag(frC + (ks * 2 + 1) * 512 + l * 8);
        const int kk = (ks - 2) * 32 + q * 8;
        #pragma unroll
        for (int mt = 0; mt < 2; mt++) {
            bf16x8 ahi, alo;
            lda_packed(RS, mt * 16 + n16, kk, ahi, alo);
            accC[mt] = MFMA(ahi, bhi, accC[mt]);
            accC[mt] = MFMA(alo, bhi, accC[mt]);
            accC[mt] = MFMA(ahi, blo, accC[mt]);
        }
    }
    // state update (sold re-read from LDS: same thread, same address)
    #pragma unroll
    for (int mt = 0; mt < 2; mt++)
        #pragma unroll
        for (int r = 0; r < 4; r++) {
            int tok = mt * 16 + q * 4 + r;
            int a = SW(tok, col);
            float u = fsigmoid(accU[mt][r] + bgu);
            float cnd = ftanh(accC[mt][r] + bcc);
            float sold = unpackf(S[a]);
            S[a] = packf(u * sold + (1.0f - u) * cnd);
        }
    __syncthreads();   // state visible; RS reads done
}

__global__ __launch_bounds__(256, 2) void gman_main(
    const float* __restrict__ X, const float* __restrict__ ws,
    const float* __restrict__ Win1, const float* __restrict__ bin1,
    const float* __restrict__ bg1, const float* __restrict__ bc1,
    const float* __restrict__ bg2, const float* __restrict__ bc2,
    const float* __restrict__ bo1, const float* __restrict__ Wo2,
    const float* __restrict__ bo2, float* __restrict__ out) {
    __shared__ u32 XE[2048], S1[2048], S2[2048], RS[2048];   // 32 KB exactly

    const int tid = threadIdx.x;
    const int l = tid & 63;
    const int w = tid >> 6;
    const int uw = __builtin_amdgcn_readfirstlane(w);
    const int n16 = l & 15, q = l >> 4;
    const int col = uw * 16 + n16;
    const int b = blockIdx.x >> 5;
    const int nb = blockIdx.x & 31;         // 32 token-groups of 32
    const int n0 = nb << 5;

    const u16* frU = (const u16*)ws;
    const u16* frG1 = frU + uw * 8192;
    const u16* frG2 = frU + 32768 + uw * 8192;
    const u16* frC1 = frU + 65536 + uw * 4096;
    const u16* frC2 = frU + 81920 + uw * 4096;
    const u16* frX  = frU + 98304 + uw * 2048;
    const u16* frH  = frU + 106496 + uw * 2048;
    // seB stays in 64-token (old-nb) groups; remap: old group = nb>>1,
    // old mt = (nb&1)*2 + mt_new
    const float* seQ = ws + 57344 + ((((nb >> 1) * 4 + uw) * 64) + l) * 16;
    const int mtBase = (nb & 1) * 2;
    const float* teo = ws + 122880;

    #pragma unroll
    for (int i = 0; i < 8; i++) { S1[tid + i * 256] = 0u; S2[tid + i * 256] = 0u; }

    f32x4 se_v[2];
    #pragma unroll
    for (int mt = 0; mt < 2; mt++)
        se_v[mt] = *(const f32x4*)(seQ + (mtBase + mt) * 4);
    const float bg1r = bg1[col], bg1u = bg1[64 + col], bc1c = bc1[col];
    const float bg2r = bg2[col], bg2u = bg2[64 + col], bc2c = bc2[col];

    __syncthreads();   // S-init visible before first use

    #pragma unroll 1
    for (int p = 0; p < 12; p++) {
        // raw x direct from global (L1-resident row; 2 values per thread)
        const float* xrow = X + (b * 12 + p) * NB + n0;
        float xm[2];
        #pragma unroll
        for (int mt = 0; mt < 2; mt++) xm[mt] = xrow[mt * 16 + n16];
        const float tev = teo[(b * 12 + p) * 64 + col];
        // xe GEMM: A = h1 = relu(x*Win1+bin1) built in regs, B = Win2 quarter
        f32x4 accX[2];
        #pragma unroll
        for (int mt = 0; mt < 2; mt++) accX[mt] = (f32x4)0.0f;
        #pragma unroll
        for (int ks = 0; ks < 2; ks++) {
            const int k0 = ks * 32 + q * 8;
            f32x4 w1a = *(const f32x4*)(Win1 + k0), w1b = *(const f32x4*)(Win1 + k0 + 4);
            f32x4 b1a = *(const f32x4*)(bin1 + k0), b1b = *(const f32x4*)(bin1 + k0 + 4);
            bf16x8 bhi = ldfrag(frX + (ks * 2 + 0) * 512 + l * 8);
            bf16x8 blo = ldfrag(frX + (ks * 2 + 1) * 512 + l * 8);
            #pragma unroll
            for (int mt = 0; mt < 2; mt++) {
                f32x4 h0, h1v;
                #pragma unroll
                for (int i = 0; i < 4; i++) {
                    h0[i]  = fmaxf(fmaf(xm[mt], w1a[i], b1a[i]), 0.0f);
                    h1v[i] = fmaxf(fmaf(xm[mt], w1b[i], b1b[i]), 0.0f);
                }
                bf16x8 ahi, alo; split8(h0, h1v, ahi, alo);
                accX[mt] = MFMA(ahi, bhi, accX[mt]);
                accX[mt] = MFMA(alo, bhi, accX[mt]);
                accX[mt] = MFMA(ahi, blo, accX[mt]);
            }
        }
        // XE write safe without pre-barrier: last XE reads (gru1 phase 1 of
        // step p-1) retired before p-1's rs barrier.
        #pragma unroll
        for (int mt = 0; mt < 2; mt++)
            #pragma unroll
            for (int r = 0; r < 4; r++) {
                int tok = mt * 16 + q * 4 + r;
                XE[SW(tok, col)] = packf(accX[mt][r] + se_v[mt][r] + tev);
            }
        __syncthreads();   // XE complete

        gru_full(XE, S1, RS, frG1, frC1, bg1r, bg1u, bc1c, l, col);
        gru_full(S1, S2, RS, frG2, frC2, bg2r, bg2u, bc2c, l, col);
    }

    // head: h = relu(S2@Wo1+bo1) via MFMA into XE (packed), then y GEMV
    f32x4 accH[2];
    #pragma unroll
    for (int mt = 0; mt < 2; mt++) accH[mt] = (f32x4)0.0f;
    #pragma unroll
    for (int ks = 0; ks < 2; ks++) {
        bf16x8 bhi = ldfrag(frH + (ks * 2 + 0) * 512 + l * 8);
        bf16x8 blo = ldfrag(frH + (ks * 2 + 1) * 512 + l * 8);
        const int kk = ks * 32 + q * 8;
        #pragma unroll
        for (int mt = 0; mt < 2; mt++) {
            bf16x8 ahi, alo;
            lda_packed(S2, mt * 16 + n16, kk, ahi, alo);
            accH[mt] = MFMA(ahi, bhi, accH[mt]);
            accH[mt] = MFMA(alo, bhi, accH[mt]);
            accH[mt] = MFMA(ahi, blo, accH[mt]);
        }
    }
    const float bo1c = bo1[col];
    #pragma unroll
    for (int mt = 0; mt < 2; mt++)
        #pragma unroll
        for (int r = 0; r < 4; r++) {
            int tok = mt * 16 + q * 4 + r;
            XE[SW(tok, col)] = packf(fmaxf(accH[mt][r] + bo1c, 0.0f));
        }
    __syncthreads();
    // y: lanes 0..31 = tokens; wave owns q-cols 3w..3w+2
    if (l < 32) {
        const int swzt = SWZ(l);
        float y0 = bo2[3 * uw + 0], y1 = bo2[3 * uw + 1], y2 = bo2[3 * uw + 2];
        #pragma unroll
        for (int c = 0; c < 16; c++) {
            i32x4 d = *(const i32x4*)(XE + l * 64 + c * 4);
            const int j0 = (c * 4) ^ swzt;
            #pragma unroll
            for (int e = 0; e < 4; e++) {
                float hj = unpackf((u32)d[e]);
                int j = j0 + e;
                y0 = fmaf(hj, Wo2[j * 12 + 3 * uw + 0], y0);
                y1 = fmaf(hj, Wo2[j * 12 + 3 * uw + 1], y1);
                y2 = fmaf(hj, Wo2[j * 12 + 3 * uw + 2], y2);
            }
        }
        out[(b * 12 + 3 * uw + 0) * NB + n0 + l] = y0;
        out[(b * 12 + 3 * uw + 1) * NB + n0 + l] = y1;
        out[(b * 12 + 3 * uw + 2) * NB + n0 + l] = y2;
    }
}

extern "C" void kernel_launch(void* const* d_in, const int* in_sizes, int n_in,
                              void* d_out, int out_size, void* d_ws, size_t ws_size,
                              hipStream_t stream) {
    const float* X    = (const float*)d_in[0];
    // d_in[1]=ZC, d_in[2]=ZF unused by the reference
    const float* SE   = (const float*)d_in[3];
    const float* Wse1 = (const float*)d_in[4];
    const float* bse1 = (const float*)d_in[5];
    const float* Wse2 = (const float*)d_in[6];
    const float* bse2 = (const float*)d_in[7];
    const float* Wte1 = (const float*)d_in[8];
    const float* bte1 = (const float*)d_in[9];
    const float* Wte2 = (const float*)d_in[10];
    const float* bte2 = (const float*)d_in[11];
    const float* Win1 = (const float*)d_in[12];
    const float* bin1 = (const float*)d_in[13];
    const float* Win2 = (const float*)d_in[14];
    const float* bin2 = (const float*)d_in[15];
    const float* Wg1  = (const float*)d_in[16];
    const float* bg1  = (const float*)d_in[17];
    const float* Wc1  = (const float*)d_in[18];
    const float* bc1  = (const float*)d_in[19];
    const float* Wg2  = (const float*)d_in[20];
    const float* bg2  = (const float*)d_in[21];
    const float* Wc2  = (const float*)d_in[22];
    const float* bc2  = (const float*)d_in[23];
    const float* Wo1  = (const float*)d_in[24];
    const float* bo1  = (const float*)d_in[25];
    const float* Wo2  = (const float*)d_in[26];
    const float* bo2  = (const float*)d_in[27];
    const int*   TE   = (const int*)d_in[28];

    float* ws = (float*)d_ws;                  // 172032 floats = 688 KB
    u16* fr = (u16*)ws;
    float* seB = ws + 57344;
    float* teo = ws + 122880;
    float* out = (float*)d_out;

    prep_all<<<476, 256, 0, stream>>>(Wg1, Wg2, Wc1, Wc2, Win2, Wo1,
                                      SE, Wse1, bse1, Wse2, bse2, bin2,
                                      TE, Wte1, bte1, Wte2, bte2,
                                      fr, seB, teo);
    gman_main<<<2048, 256, 0, stream>>>(X, ws, Win1, bin1, bg1, bc1, bg2, bc2,
                                        bo1, Wo2, bo2, out);
}

// Round 17
// 548.046 us; speedup vs baseline: 5.6988x; 1.1438x over previous
//
#include <hip/hip_runtime.h>

// GMAN pipeline, fully fused, MFMA edition. support = I -> per-block token GEMMs.
// B=64, P=Q=12, N=1024, D=64. Output [B,Q,N] fp32.
//
// R28 = R24 (best: 470us main, 540.7 total) + two finishers.
// Evidence trail:
//  - R27: 32KB LDS -> occupancy STILL 22.8%. Full ledger {84/48K, 128/32K..
//    80K, 512thr} all pin at ~8 waves/CU -> occupancy closed permanently;
//    doubled block count also doubled frag stream (FETCH 1.0GB) -> 565us.
//  - Ledger mining: the "flat" WRITE ~126MB in every good config is ~120
//    dw/thread RESIDUAL SPILL (output is 3MB). Live set at 128 regs is
//    marginally over. se_v[4] = 16 always-live VGPRs consumed only in the
//    xe epilogue -> demote to per-use loads (L2-hot). Readout: WRITE <30MB.
//  - T5 setprio around gru MFMA phases: 2 independent blocks/CU drift out
//    of phase (catalog precondition); MFMA-phase block preempts the other's
//    VALU phases. Zero reg cost. Readout: MfmaUtil.
// Tripwire: dur >480us -> revert both, finalize R24.

#define NB 1024

typedef float f32x4 __attribute__((ext_vector_type(4)));
typedef __bf16 bf16x8 __attribute__((ext_vector_type(8)));
typedef int i32x4 __attribute__((ext_vector_type(4)));
typedef unsigned int u32;
typedef unsigned short u16;

#define MFMA(a, b, c) __builtin_amdgcn_mfma_f32_16x16x32_bf16(a, b, c, 0, 0, 0)

__device__ __forceinline__ float fexp(float x) {
    return __builtin_amdgcn_exp2f(x * 1.44269504088896341f);
}
__device__ __forceinline__ float fsigmoid(float x) {
    return __builtin_amdgcn_rcpf(1.0f + fexp(-x));
}
__device__ __forceinline__ float ftanh(float x) {
    return 1.0f - 2.0f * __builtin_amdgcn_rcpf(1.0f + fexp(2.0f * x));
}

// pack fp32 -> {bf16 hi | bf16 lo} in one dword (truncation split)
__device__ __forceinline__ u32 packf(float v) {
    u32 u = __builtin_bit_cast(u32, v);
    u32 hb = u & 0xFFFF0000u;
    float lo = v - __builtin_bit_cast(float, hb);
    return hb | (__builtin_bit_cast(u32, lo) >> 16);
}
__device__ __forceinline__ float unpackf(u32 u) {
    return __builtin_bit_cast(float, u & 0xFFFF0000u)
         + __builtin_bit_cast(float, u << 16);
}

__device__ __forceinline__ bf16x8 ldfrag(const u16* p) {
    i32x4 t = *(const i32x4*)p;
    return __builtin_bit_cast(bf16x8, t);
}
// fragment load from an LDS-staged table (ds_read_b128)
__device__ __forceinline__ bf16x8 ldfragL(const u32* p) {
    i32x4 t = *(const i32x4*)p;
    return __builtin_bit_cast(bf16x8, t);
}
__device__ __forceinline__ void split8(f32x4 a0, f32x4 a1, bf16x8& hi, bf16x8& lo) {
    #pragma unroll
    for (int i = 0; i < 4; i++) {
        __bf16 h0 = (__bf16)a0[i]; hi[i] = h0;     lo[i] = (__bf16)(a0[i] - (float)h0);
        __bf16 h1 = (__bf16)a1[i]; hi[4 + i] = h1; lo[4 + i] = (__bf16)(a1[i] - (float)h1);
    }
}

// swizzle: xor k bits 2..4 by t bits; k bits 0-1 intact -> 4-dword windows legal
#define SWZ(t) ((((t) & 3) << 3) ^ ((t) & 4) ^ (((t) & 8) << 1))
#define SW(t, k) ((t) * 64 + ((k) ^ SWZ(t)))

// read packed A-frag: 8 consecutive k from swizzled row m, extract hi/lo via v_perm
__device__ __forceinline__ void lda_packed(const u32* __restrict__ src, int m, int kk,
                                           bf16x8& hi, bf16x8& lo) {
    const int sk = kk ^ SWZ(m);
    i32x4 d0 = *(const i32x4*)(src + m * 64 + sk);
    i32x4 d1 = *(const i32x4*)(src + m * 64 + (sk ^ 4));
    i32x4 h, L;
    h[0] = (int)__builtin_amdgcn_perm((u32)d0[1], (u32)d0[0], 0x07060302u);
    h[1] = (int)__builtin_amdgcn_perm((u32)d0[3], (u32)d0[2], 0x07060302u);
    h[2] = (int)__builtin_amdgcn_perm((u32)d1[1], (u32)d1[0], 0x07060302u);
    h[3] = (int)__builtin_amdgcn_perm((u32)d1[3], (u32)d1[2], 0x07060302u);
    L[0] = (int)__builtin_amdgcn_perm((u32)d0[1], (u32)d0[0], 0x05040100u);
    L[1] = (int)__builtin_amdgcn_perm((u32)d0[3], (u32)d0[2], 0x05040100u);
    L[2] = (int)__builtin_amdgcn_perm((u32)d1[1], (u32)d1[0], 0x05040100u);
    L[3] = (int)__builtin_amdgcn_perm((u32)d1[3], (u32)d1[2], 0x05040100u);
    hi = __builtin_bit_cast(bf16x8, h);
    lo = __builtin_bit_cast(bf16x8, L);
}

// ---------------- ws layout (dwords) ----------------
// 0      FR_G1 [wq][nt][ks][half][lane][8bf16] 16384 dw ; 16384 FR_G2
// 32768  FR_C1 [wq][ks][half][lane][8] 8192 dw ; 40960 FR_C2
// 49152  FR_XE Win2 ; 53248 FR_HD Wo1
// 57344  seB [nb(16)][w(4)][lane(64)][16] fp32 (b_in2 folded)  65536 dw
// 122880 teo [768][64] fp32

__device__ __forceinline__ void wsplit(float v, u16* dhi, u16* dlo) {
    __bf16 h = (__bf16)v;
    __bf16 l = (__bf16)(v - (float)h);
    *dhi = __builtin_bit_cast(u16, h);
    *dlo = __builtin_bit_cast(u16, l);
}

// ONE fused prep kernel. Branch on blockIdx range (block-uniform -> barriers
// legal). Blocks: [0,16) gates, [16,24) cand, [24,28) small,
// [28,284) se (4 rows/block), [284,476) te (4 rows/block). 256 threads.
__global__ void prep_all(
    const float* __restrict__ Wg1, const float* __restrict__ Wg2,
    const float* __restrict__ Wc1, const float* __restrict__ Wc2,
    const float* __restrict__ Win2, const float* __restrict__ Wo1,
    const float* __restrict__ SE, const float* __restrict__ Wse1,
    const float* __restrict__ bse1, const float* __restrict__ Wse2,
    const float* __restrict__ bse2, const float* __restrict__ bin2,
    const int* __restrict__ TE, const float* __restrict__ Wte1,
    const float* __restrict__ bte1, const float* __restrict__ Wte2,
    const float* __restrict__ bte2,
    u16* __restrict__ fr, float* __restrict__ seB, float* __restrict__ teo) {
    __shared__ float hsh[4][64];
    const int bid = blockIdx.x, tid = threadIdx.x;
    if (bid < 16) {                       // ---- gates
        int i = bid * 256 + tid;          // [0, 4096)
        int layer = i >> 11, r = i & 2047;
        int w = r >> 9; r &= 511; int nt = r >> 8; r &= 255;
        int ks = r >> 6; int lane = r & 63;
        const float* Wg = layer ? Wg2 : Wg1;
        int n = lane & 15, q = lane >> 4;
        int col = nt ? (64 + w * 16 + n) : (w * 16 + n);
        u16* dst = fr + layer * 32768 + (((w * 2 + nt) * 4 + ks) * 2) * 512 + lane * 8;
        #pragma unroll
        for (int j = 0; j < 8; j++) {
            int k = ks * 32 + q * 8 + j;
            float v = Wg[k * 128 + col] + Wg[(k + 128) * 128 + col];
            wsplit(v, dst + j, dst + 512 + j);
        }
    } else if (bid < 24) {                // ---- cand
        int i = (bid - 16) * 256 + tid;   // [0, 2048)
        int layer = i >> 10, r = i & 1023;
        int w = r >> 8; r &= 255; int ks = r >> 6; int lane = r & 63;
        const float* Wc = layer ? Wc2 : Wc1;
        int n = lane & 15, q = lane >> 4;
        int col = w * 16 + n;
        u16* dst = fr + 65536 + layer * 16384 + ((w * 4 + ks) * 2) * 512 + lane * 8;
        #pragma unroll
        for (int j = 0; j < 8; j++) {
            int k = ks * 32 + q * 8 + j;
            float v = Wc[k * 64 + col] + Wc[(k + 128) * 64 + col];
            wsplit(v, dst + j, dst + 512 + j);
        }
    } else if (bid < 28) {                // ---- small (Win2 / Wo1)
        int i = (bid - 24) * 256 + tid;   // [0, 1024)
        int kind = i >> 9, r = i & 511;
        int w = r >> 7; r &= 127; int ks = r >> 6; int lane = r & 63;
        const float* W = kind ? Wo1 : Win2;
        int n = lane & 15, q = lane >> 4;
        int col = w * 16 + n;
        u16* dst = fr + 98304 + kind * 8192 + ((w * 2 + ks) * 2) * 512 + lane * 8;
        #pragma unroll
        for (int j = 0; j < 8; j++) {
            int k = ks * 32 + q * 8 + j;
            float v = W[k * 64 + col];
            wsplit(v, dst + j, dst + 512 + j);
        }
    } else if (bid < 284) {               // ---- se: 4 rows per block
        int sb = tid >> 6, d = tid & 63;
        int n = (bid - 28) * 4 + sb;      // [0, 1024)
        float acc = bse1[d];
        for (int k = 0; k < 64; k++) acc = fmaf(SE[n * 64 + k], Wse1[k * 64 + d], acc);
        hsh[sb][d] = fmaxf(acc, 0.0f);
        __syncthreads();
        float acc2 = bse2[d];
        for (int k = 0; k < 64; k++) acc2 = fmaf(hsh[sb][k], Wse2[k * 64 + d], acc2);
        int nb = n >> 6, tok = n & 63;
        int mt = tok >> 4, q = (tok >> 2) & 3, r = tok & 3;
        int w = d >> 4, n16 = d & 15;
        seB[(((nb * 4 + w) * 64) + q * 16 + n16) * 16 + mt * 4 + r] = acc2 + bin2[d];
    } else {                              // ---- te: 4 rows per block
        int sb = tid >> 6, d = tid & 63;
        int bp = (bid - 284) * 4 + sb;    // [0, 768)
        int b = bp / 12, p = bp - b * 12;
        int dow = TE[(b * 24 + p) * 2 + 0];
        int tod = TE[(b * 24 + p) * 2 + 1];
        float v = Wte1[dow * 64 + d] + Wte1[(7 + tod) * 64 + d] + bte1[d];
        hsh[sb][d] = fmaxf(v, 0.0f);
        __syncthreads();
        float acc = bte2[d];
        for (int k = 0; k < 64; k++) acc = fmaf(hsh[sb][k], Wte2[k * 64 + d], acc);
        teo[bp * 64 + d] = acc;
    }
}

// full GRU step. Wave owns cols [16w,16w+16). Gate + cand fragments streamed
// from ws (L2-resident; remat beats spill at the 128-reg budget). RS is a
// SEPARATE buffer (alias is spill-bait: R19). No soldv (R15 lesson).
// setprio(1) during MFMA/ds_read phases (T5: 2 independent blocks/CU drift
// out of phase -> MFMA-phase block preempts the other's VALU phases).
__device__ __forceinline__ void gru_full(
    const u32* __restrict__ XIN, u32* __restrict__ S, u32* __restrict__ RS,
    const u16* __restrict__ frG, const u16* __restrict__ frC,
    float bgr, float bgu, float bcc, int l, int col) {
    const int n16 = l & 15, q = l >> 4;
    f32x4 accR[4], accU[4], accC[4];
    #pragma unroll
    for (int mt = 0; mt < 4; mt++) {
        accR[mt] = (f32x4)0.0f; accU[mt] = (f32x4)0.0f; accC[mt] = (f32x4)0.0f;
    }
    __builtin_amdgcn_s_setprio(1);
    // phase 1: ks 0..1 (XIN K-half): one A-frag feeds R+U+C
    #pragma unroll
    for (int ks = 0; ks < 2; ks++) {
        bf16x8 gRh = ldfrag(frG + (ks * 2 + 0) * 512 + l * 8);
        bf16x8 gRl = ldfrag(frG + (ks * 2 + 1) * 512 + l * 8);
        bf16x8 gUh = ldfrag(frG + (8 + ks * 2 + 0) * 512 + l * 8);
        bf16x8 gUl = ldfrag(frG + (8 + ks * 2 + 1) * 512 + l * 8);
        bf16x8 bhiC = ldfrag(frC + (ks * 2 + 0) * 512 + l * 8);
        bf16x8 bloC = ldfrag(frC + (ks * 2 + 1) * 512 + l * 8);
        const int kk = ks * 32 + q * 8;
        #pragma unroll
        for (int mt = 0; mt < 4; mt++) {
            bf16x8 ahi, alo;
            lda_packed(XIN, mt * 16 + n16, kk, ahi, alo);
            accR[mt] = MFMA(ahi, gRh, accR[mt]);
            accR[mt] = MFMA(alo, gRh, accR[mt]);
            accR[mt] = MFMA(ahi, gRl, accR[mt]);
            accU[mt] = MFMA(ahi, gUh, accU[mt]);
            accU[mt] = MFMA(alo, gUh, accU[mt]);
            accU[mt] = MFMA(ahi, gUl, accU[mt]);
            accC[mt] = MFMA(ahi, bhiC, accC[mt]);
            accC[mt] = MFMA(alo, bhiC, accC[mt]);
            accC[mt] = MFMA(ahi, bloC, accC[mt]);
        }
    }
    // phase 2: ks 2..3 (S K-half): gates only
    #pragma unroll
    for (int ks = 2; ks < 4; ks++) {
        bf16x8 gRh = ldfrag(frG + (ks * 2 + 0) * 512 + l * 8);
        bf16x8 gRl = ldfrag(frG + (ks * 2 + 1) * 512 + l * 8);
        bf16x8 gUh = ldfrag(frG + (8 + ks * 2 + 0) * 512 + l * 8);
        bf16x8 gUl = ldfrag(frG + (8 + ks * 2 + 1) * 512 + l * 8);
        const int kk = (ks - 2) * 32 + q * 8;
        #pragma unroll
        for (int mt = 0; mt < 4; mt++) {
            bf16x8 ahi, alo;
            lda_packed(S, mt * 16 + n16, kk, ahi, alo);
            accR[mt] = MFMA(ahi, gRh, accR[mt]);
            accR[mt] = MFMA(alo, gRh, accR[mt]);
            accR[mt] = MFMA(ahi, gRl, accR[mt]);
            accU[mt] = MFMA(ahi, gUh, accU[mt]);
            accU[mt] = MFMA(alo, gUh, accU[mt]);
            accU[mt] = MFMA(ahi, gUl, accU[mt]);
        }
    }
    __builtin_amdgcn_s_setprio(0);
    // rs = sigmoid(r) * s (RS separate buffer -> no barrier needed first)
    #pragma unroll
    for (int mt = 0; mt < 4; mt++)
        #pragma unroll
        for (int r = 0; r < 4; r++) {
            int tok = mt * 16 + q * 4 + r;
            int a = SW(tok, col);
            RS[a] = packf(fsigmoid(accR[mt][r] + bgr) * unpackf(S[a]));
        }
    __syncthreads();   // rs visible
    __builtin_amdgcn_s_setprio(1);
    // cand ks 2..3 (RS K-half)
    #pragma unroll
    for (int ks = 2; ks < 4; ks++) {
        bf16x8 bhi = ldfrag(frC + (ks * 2 + 0) * 512 + l * 8);
        bf16x8 blo = ldfrag(frC + (ks * 2 + 1) * 512 + l * 8);
        const int kk = (ks - 2) * 32 + q * 8;
        #pragma unroll
        for (int mt = 0; mt < 4; mt++) {
            bf16x8 ahi, alo;
            lda_packed(RS, mt * 16 + n16, kk, ahi, alo);
            accC[mt] = MFMA(ahi, bhi, accC[mt]);
            accC[mt] = MFMA(alo, bhi, accC[mt]);
            accC[mt] = MFMA(ahi, blo, accC[mt]);
        }
    }
    __builtin_amdgcn_s_setprio(0);
    // state update (sold re-read from LDS: same thread, same address)
    #pragma unroll
    for (int mt = 0; mt < 4; mt++)
        #pragma unroll
        for (int r = 0; r < 4; r++) {
            int tok = mt * 16 + q * 4 + r;
            int a = SW(tok, col);
            float u = fsigmoid(accU[mt][r] + bgu);
            float cnd = ftanh(accC[mt][r] + bcc);
            float sold = unpackf(S[a]);
            S[a] = packf(u * sold + (1.0f - u) * cnd);
        }
    __syncthreads();   // state visible; RS reads done
}

__global__ __launch_bounds__(256, 2) void gman_main(
    const float* __restrict__ X, const float* __restrict__ ws,
    const float* __restrict__ Win1, const float* __restrict__ bin1,
    const float* __restrict__ bg1, const float* __restrict__ bc1,
    const float* __restrict__ bg2, const float* __restrict__ bc2,
    const float* __restrict__ bo1, const float* __restrict__ Wo2,
    const float* __restrict__ bo2, float* __restrict__ out) {
    __shared__ u32 XE[4096], S1[4096], S2[4096], RS[4096];   // 64 KB
    __shared__ u32 FRX[4096];                                // +16 KB Win2 frags
    // total 80 KB; 2 blocks/CU

    const int tid = threadIdx.x;
    const int l = tid & 63;
    const int w = tid >> 6;
    const int uw = __builtin_amdgcn_readfirstlane(w);
    const int n16 = l & 15, q = l >> 4;
    const int col = uw * 16 + n16;
    const int b = blockIdx.x >> 4;
    const int nb = blockIdx.x & 15;
    const int n0 = nb << 6;

    const u16* frU = (const u16*)ws;
    const u16* frG1 = frU + uw * 8192;
    const u16* frG2 = frU + 32768 + uw * 8192;
    const u16* frC1 = frU + 65536 + uw * 4096;
    const u16* frC2 = frU + 81920 + uw * 4096;
    const u16* frH  = frU + 106496 + uw * 2048;
    const float* seQ = ws + 57344 + (((nb * 4 + uw) * 64) + l) * 16;
    const float* teo = ws + 122880;

    // stage Win2 frag table (FR_XE, dwords 49152..53247) into LDS
    const u32* frXsrc = (const u32*)ws + 49152;
    #pragma unroll
    for (int i = 0; i < 16; i++) FRX[tid + i * 256] = frXsrc[tid + i * 256];
    const u32* frXL = FRX + uw * 1024;   // per-wave quarter, dword units

    #pragma unroll
    for (int i = 0; i < 16; i++) { S1[tid + i * 256] = 0u; S2[tid + i * 256] = 0u; }

    const float bg1r = bg1[col], bg1u = bg1[64 + col], bc1c = bc1[col];
    const float bg2r = bg2[col], bg2u = bg2[64 + col], bc2c = bc2[col];

    __syncthreads();   // FRX + S-init visible before first use

    #pragma unroll 1
    for (int p = 0; p < 12; p++) {
        // raw x direct from global (L1-resident row; 4 values per thread)
        const float* xrow = X + (b * 12 + p) * NB + n0;
        float xm[4];
        #pragma unroll
        for (int mt = 0; mt < 4; mt++) xm[mt] = xrow[mt * 16 + n16];
        const float tev = teo[(b * 12 + p) * 64 + col];
        // xe GEMM: A = h1 = relu(x*Win1+bin1) built in regs, B = Win2 quarter (LDS)
        f32x4 accX[4];
        #pragma unroll
        for (int mt = 0; mt < 4; mt++) accX[mt] = (f32x4)0.0f;
        #pragma unroll
        for (int ks = 0; ks < 2; ks++) {
            const int k0 = ks * 32 + q * 8;
            f32x4 w1a = *(const f32x4*)(Win1 + k0), w1b = *(const f32x4*)(Win1 + k0 + 4);
            f32x4 b1a = *(const f32x4*)(bin1 + k0), b1b = *(const f32x4*)(bin1 + k0 + 4);
            bf16x8 bhi = ldfragL(frXL + (ks * 2 + 0) * 256 + l * 4);
            bf16x8 blo = ldfragL(frXL + (ks * 2 + 1) * 256 + l * 4);
            #pragma unroll
            for (int mt = 0; mt < 4; mt++) {
                f32x4 h0, h1v;
                #pragma unroll
                for (int i = 0; i < 4; i++) {
                    h0[i]  = fmaxf(fmaf(xm[mt], w1a[i], b1a[i]), 0.0f);
                    h1v[i] = fmaxf(fmaf(xm[mt], w1b[i], b1b[i]), 0.0f);
                }
                bf16x8 ahi, alo; split8(h0, h1v, ahi, alo);
                accX[mt] = MFMA(ahi, bhi, accX[mt]);
                accX[mt] = MFMA(alo, bhi, accX[mt]);
                accX[mt] = MFMA(ahi, blo, accX[mt]);
            }
        }
        // XE write safe without pre-barrier: last XE reads (gru1 phase 1 of
        // step p-1) retired before p-1's rs barrier.
        // se read per-use (frees 16 always-live VGPRs across gru bodies).
        #pragma unroll
        for (int mt = 0; mt < 4; mt++) {
            f32x4 sev = *(const f32x4*)(seQ + mt * 4);
            #pragma unroll
            for (int r = 0; r < 4; r++) {
                int tok = mt * 16 + q * 4 + r;
                XE[SW(tok, col)] = packf(accX[mt][r] + sev[r] + tev);
            }
        }
        __syncthreads();   // XE complete

        gru_full(XE, S1, RS, frG1, frC1, bg1r, bg1u, bc1c, l, col);
        gru_full(S1, S2, RS, frG2, frC2, bg2r, bg2u, bc2c, l, col);
    }

    // head: h = relu(S2@Wo1+bo1) via MFMA into XE (packed), then y GEMV
    f32x4 accH[4];
    #pragma unroll
    for (int mt = 0; mt < 4; mt++) accH[mt] = (f32x4)0.0f;
    #pragma unroll
    for (int ks = 0; ks < 2; ks++) {
        bf16x8 bhi = ldfrag(frH + (ks * 2 + 0) * 512 + l * 8);
        bf16x8 blo = ldfrag(frH + (ks * 2 + 1) * 512 + l * 8);
        const int kk = ks * 32 + q * 8;
        #pragma unroll
        for (int mt = 0; mt < 4; mt++) {
            bf16x8 ahi, alo;
            lda_packed(S2, mt * 16 + n16, kk, ahi, alo);
            accH[mt] = MFMA(ahi, bhi, accH[mt]);
            accH[mt] = MFMA(alo, bhi, accH[mt]);
            accH[mt] = MFMA(ahi, blo, accH[mt]);
        }
    }
    const float bo1c = bo1[col];
    #pragma unroll
    for (int mt = 0; mt < 4; mt++)
        #pragma unroll
        for (int r = 0; r < 4; r++) {
            int tok = mt * 16 + q * 4 + r;
            XE[SW(tok, col)] = packf(fmaxf(accH[mt][r] + bo1c, 0.0f));
        }
    __syncthreads();
    // y: lane = token, wave owns q-cols 3w..3w+2
    const int swzt = SWZ(l);
    float y0 = bo2[3 * uw + 0], y1 = bo2[3 * uw + 1], y2 = bo2[3 * uw + 2];
    #pragma unroll
    for (int c = 0; c < 16; c++) {
        i32x4 d = *(const i32x4*)(XE + l * 64 + c * 4);
        const int j0 = (c * 4) ^ swzt;
        #pragma unroll
        for (int e = 0; e < 4; e++) {
            float hj = unpackf((u32)d[e]);
            int j = j0 + e;
            y0 = fmaf(hj, Wo2[j * 12 + 3 * uw + 0], y0);
            y1 = fmaf(hj, Wo2[j * 12 + 3 * uw + 1], y1);
            y2 = fmaf(hj, Wo2[j * 12 + 3 * uw + 2], y2);
        }
    }
    out[(b * 12 + 3 * uw + 0) * NB + n0 + l] = y0;
    out[(b * 12 + 3 * uw + 1) * NB + n0 + l] = y1;
    out[(b * 12 + 3 * uw + 2) * NB + n0 + l] = y2;
}

extern "C" void kernel_launch(void* const* d_in, const int* in_sizes, int n_in,
                              void* d_out, int out_size, void* d_ws, size_t ws_size,
                              hipStream_t stream) {
    const float* X    = (const float*)d_in[0];
    // d_in[1]=ZC, d_in[2]=ZF unused by the reference
    const float* SE   = (const float*)d_in[3];
    const float* Wse1 = (const float*)d_in[4];
    const float* bse1 = (const float*)d_in[5];
    const float* Wse2 = (const float*)d_in[6];
    const float* bse2 = (const float*)d_in[7];
    const float* Wte1 = (const float*)d_in[8];
    const float* bte1 = (const float*)d_in[9];
    const float* Wte2 = (const float*)d_in[10];
    const float* bte2 = (const float*)d_in[11];
    const float* Win1 = (const float*)d_in[12];
    const float* bin1 = (const float*)d_in[13];
    const float* Win2 = (const float*)d_in[14];
    const float* bin2 = (const float*)d_in[15];
    const float* Wg1  = (const float*)d_in[16];
    const float* bg1  = (const float*)d_in[17];
    const float* Wc1  = (const float*)d_in[18];
    const float* bc1  = (const float*)d_in[19];
    const float* Wg2  = (const float*)d_in[20];
    const float* bg2  = (const float*)d_in[21];
    const float* Wc2  = (const float*)d_in[22];
    const float* bc2  = (const float*)d_in[23];
    const float* Wo1  = (const float*)d_in[24];
    const float* bo1  = (const float*)d_in[25];
    const float* Wo2  = (const float*)d_in[26];
    const float* bo2  = (const float*)d_in[27];
    const int*   TE   = (const int*)d_in[28];

    float* ws = (float*)d_ws;                  // 172032 floats = 688 KB
    u16* fr = (u16*)ws;
    float* seB = ws + 57344;
    float* teo = ws + 122880;
    float* out = (float*)d_out;

    prep_all<<<476, 256, 0, stream>>>(Wg1, Wg2, Wc1, Wc2, Win2, Wo1,
                                      SE, Wse1, bse1, Wse2, bse2, bin2,
                                      TE, Wte1, bte1, Wte2, bte2,
                                      fr, seB, teo);
    gman_main<<<1024, 256, 0, stream>>>(X, ws, Win1, bin1, bg1, bc1, bg2, bc2,
                                        bo1, Wo2, bo2, out);
}

// Round 18
// 535.069 us; speedup vs baseline: 5.8370x; 1.0243x over previous
//
#include <hip/hip_runtime.h>

// GMAN pipeline, fully fused, MFMA edition. support = I -> per-block token GEMMs.
// B=64, P=Q=12, N=1024, D=64. Output [B,Q,N] fp32.
//
// R29 = FINAL = R24 verbatim (best measured: 470us main dispatch, 540.7us
// total; session start was 510/575.8).
// Converged-state evidence (17 rounds):
//  - Occupancy pinned at 8 waves/CU across {32,48,64,80 KB LDS} x {84,128
//    regs} x {256,512 thr} (R12-R27) -> not grantable from source.
//  - Format: packed hi|lo dword is optimal at 128 regs; split planes kill
//    384 v_perm but add ~128MB structural spill, net -200us (R21/R22).
//  - Barriers: 5/p-step is the provable minimum for cross-wave decomposition
//    (R20 removed the removable 2); barrier-free token-private multiplies
//    the weight stream 4x -> 6.4x slower (R26); xe-fold spills (R23).
//  - Byte cuts beyond FRX are latency-hidden (R16); setprio/se_v-demotion
//    neutral (R28); sched fences neutral (R22).
// Ceiling arithmetic: 1.66 TB/s (26% HBM), MFMA-busy 108us (23%), VALU-busy
// 207us (44%, fp32-emulation tax), 33% no-issue = barrier drain + latency at
// 2 waves/SIMD. Needs fp32 MFMA / >8 waves/CU / weight-stationary D=64
// layout to go lower -- none exist on CDNA4.

#define NB 1024

typedef float f32x4 __attribute__((ext_vector_type(4)));
typedef __bf16 bf16x8 __attribute__((ext_vector_type(8)));
typedef int i32x4 __attribute__((ext_vector_type(4)));
typedef unsigned int u32;
typedef unsigned short u16;

#define MFMA(a, b, c) __builtin_amdgcn_mfma_f32_16x16x32_bf16(a, b, c, 0, 0, 0)

__device__ __forceinline__ float fexp(float x) {
    return __builtin_amdgcn_exp2f(x * 1.44269504088896341f);
}
__device__ __forceinline__ float fsigmoid(float x) {
    return __builtin_amdgcn_rcpf(1.0f + fexp(-x));
}
__device__ __forceinline__ float ftanh(float x) {
    return 1.0f - 2.0f * __builtin_amdgcn_rcpf(1.0f + fexp(2.0f * x));
}

// pack fp32 -> {bf16 hi | bf16 lo} in one dword (truncation split)
__device__ __forceinline__ u32 packf(float v) {
    u32 u = __builtin_bit_cast(u32, v);
    u32 hb = u & 0xFFFF0000u;
    float lo = v - __builtin_bit_cast(float, hb);
    return hb | (__builtin_bit_cast(u32, lo) >> 16);
}
__device__ __forceinline__ float unpackf(u32 u) {
    return __builtin_bit_cast(float, u & 0xFFFF0000u)
         + __builtin_bit_cast(float, u << 16);
}

__device__ __forceinline__ bf16x8 ldfrag(const u16* p) {
    i32x4 t = *(const i32x4*)p;
    return __builtin_bit_cast(bf16x8, t);
}
// fragment load from an LDS-staged table (ds_read_b128)
__device__ __forceinline__ bf16x8 ldfragL(const u32* p) {
    i32x4 t = *(const i32x4*)p;
    return __builtin_bit_cast(bf16x8, t);
}
__device__ __forceinline__ void split8(f32x4 a0, f32x4 a1, bf16x8& hi, bf16x8& lo) {
    #pragma unroll
    for (int i = 0; i < 4; i++) {
        __bf16 h0 = (__bf16)a0[i]; hi[i] = h0;     lo[i] = (__bf16)(a0[i] - (float)h0);
        __bf16 h1 = (__bf16)a1[i]; hi[4 + i] = h1; lo[4 + i] = (__bf16)(a1[i] - (float)h1);
    }
}

// swizzle: xor k bits 2..4 by t bits; k bits 0-1 intact -> 4-dword windows legal
#define SWZ(t) ((((t) & 3) << 3) ^ ((t) & 4) ^ (((t) & 8) << 1))
#define SW(t, k) ((t) * 64 + ((k) ^ SWZ(t)))

// read packed A-frag: 8 consecutive k from swizzled row m, extract hi/lo via v_perm
__device__ __forceinline__ void lda_packed(const u32* __restrict__ src, int m, int kk,
                                           bf16x8& hi, bf16x8& lo) {
    const int sk = kk ^ SWZ(m);
    i32x4 d0 = *(const i32x4*)(src + m * 64 + sk);
    i32x4 d1 = *(const i32x4*)(src + m * 64 + (sk ^ 4));
    i32x4 h, L;
    h[0] = (int)__builtin_amdgcn_perm((u32)d0[1], (u32)d0[0], 0x07060302u);
    h[1] = (int)__builtin_amdgcn_perm((u32)d0[3], (u32)d0[2], 0x07060302u);
    h[2] = (int)__builtin_amdgcn_perm((u32)d1[1], (u32)d1[0], 0x07060302u);
    h[3] = (int)__builtin_amdgcn_perm((u32)d1[3], (u32)d1[2], 0x07060302u);
    L[0] = (int)__builtin_amdgcn_perm((u32)d0[1], (u32)d0[0], 0x05040100u);
    L[1] = (int)__builtin_amdgcn_perm((u32)d0[3], (u32)d0[2], 0x05040100u);
    L[2] = (int)__builtin_amdgcn_perm((u32)d1[1], (u32)d1[0], 0x05040100u);
    L[3] = (int)__builtin_amdgcn_perm((u32)d1[3], (u32)d1[2], 0x05040100u);
    hi = __builtin_bit_cast(bf16x8, h);
    lo = __builtin_bit_cast(bf16x8, L);
}

// ---------------- ws layout (dwords) ----------------
// 0      FR_G1 [wq][nt][ks][half][lane][8bf16] 16384 dw ; 16384 FR_G2
// 32768  FR_C1 [wq][ks][half][lane][8] 8192 dw ; 40960 FR_C2
// 49152  FR_XE Win2 ; 53248 FR_HD Wo1
// 57344  seB [nb(16)][w(4)][lane(64)][16] fp32 (b_in2 folded)  65536 dw
// 122880 teo [768][64] fp32

__device__ __forceinline__ void wsplit(float v, u16* dhi, u16* dlo) {
    __bf16 h = (__bf16)v;
    __bf16 l = (__bf16)(v - (float)h);
    *dhi = __builtin_bit_cast(u16, h);
    *dlo = __builtin_bit_cast(u16, l);
}

// ONE fused prep kernel. Branch on blockIdx range (block-uniform -> barriers
// legal). Blocks: [0,16) gates, [16,24) cand, [24,28) small,
// [28,284) se (4 rows/block), [284,476) te (4 rows/block). 256 threads.
__global__ void prep_all(
    const float* __restrict__ Wg1, const float* __restrict__ Wg2,
    const float* __restrict__ Wc1, const float* __restrict__ Wc2,
    const float* __restrict__ Win2, const float* __restrict__ Wo1,
    const float* __restrict__ SE, const float* __restrict__ Wse1,
    const float* __restrict__ bse1, const float* __restrict__ Wse2,
    const float* __restrict__ bse2, const float* __restrict__ bin2,
    const int* __restrict__ TE, const float* __restrict__ Wte1,
    const float* __restrict__ bte1, const float* __restrict__ Wte2,
    const float* __restrict__ bte2,
    u16* __restrict__ fr, float* __restrict__ seB, float* __restrict__ teo) {
    __shared__ float hsh[4][64];
    const int bid = blockIdx.x, tid = threadIdx.x;
    if (bid < 16) {                       // ---- gates
        int i = bid * 256 + tid;          // [0, 4096)
        int layer = i >> 11, r = i & 2047;
        int w = r >> 9; r &= 511; int nt = r >> 8; r &= 255;
        int ks = r >> 6; int lane = r & 63;
        const float* Wg = layer ? Wg2 : Wg1;
        int n = lane & 15, q = lane >> 4;
        int col = nt ? (64 + w * 16 + n) : (w * 16 + n);
        u16* dst = fr + layer * 32768 + (((w * 2 + nt) * 4 + ks) * 2) * 512 + lane * 8;
        #pragma unroll
        for (int j = 0; j < 8; j++) {
            int k = ks * 32 + q * 8 + j;
            float v = Wg[k * 128 + col] + Wg[(k + 128) * 128 + col];
            wsplit(v, dst + j, dst + 512 + j);
        }
    } else if (bid < 24) {                // ---- cand
        int i = (bid - 16) * 256 + tid;   // [0, 2048)
        int layer = i >> 10, r = i & 1023;
        int w = r >> 8; r &= 255; int ks = r >> 6; int lane = r & 63;
        const float* Wc = layer ? Wc2 : Wc1;
        int n = lane & 15, q = lane >> 4;
        int col = w * 16 + n;
        u16* dst = fr + 65536 + layer * 16384 + ((w * 4 + ks) * 2) * 512 + lane * 8;
        #pragma unroll
        for (int j = 0; j < 8; j++) {
            int k = ks * 32 + q * 8 + j;
            float v = Wc[k * 64 + col] + Wc[(k + 128) * 64 + col];
            wsplit(v, dst + j, dst + 512 + j);
        }
    } else if (bid < 28) {                // ---- small (Win2 / Wo1)
        int i = (bid - 24) * 256 + tid;   // [0, 1024)
        int kind = i >> 9, r = i & 511;
        int w = r >> 7; r &= 127; int ks = r >> 6; int lane = r & 63;
        const float* W = kind ? Wo1 : Win2;
        int n = lane & 15, q = lane >> 4;
        int col = w * 16 + n;
        u16* dst = fr + 98304 + kind * 8192 + ((w * 2 + ks) * 2) * 512 + lane * 8;
        #pragma unroll
        for (int j = 0; j < 8; j++) {
            int k = ks * 32 + q * 8 + j;
            float v = W[k * 64 + col];
            wsplit(v, dst + j, dst + 512 + j);
        }
    } else if (bid < 284) {               // ---- se: 4 rows per block
        int sb = tid >> 6, d = tid & 63;
        int n = (bid - 28) * 4 + sb;      // [0, 1024)
        float acc = bse1[d];
        for (int k = 0; k < 64; k++) acc = fmaf(SE[n * 64 + k], Wse1[k * 64 + d], acc);
        hsh[sb][d] = fmaxf(acc, 0.0f);
        __syncthreads();
        float acc2 = bse2[d];
        for (int k = 0; k < 64; k++) acc2 = fmaf(hsh[sb][k], Wse2[k * 64 + d], acc2);
        int nb = n >> 6, tok = n & 63;
        int mt = tok >> 4, q = (tok >> 2) & 3, r = tok & 3;
        int w = d >> 4, n16 = d & 15;
        seB[(((nb * 4 + w) * 64) + q * 16 + n16) * 16 + mt * 4 + r] = acc2 + bin2[d];
    } else {                              // ---- te: 4 rows per block
        int sb = tid >> 6, d = tid & 63;
        int bp = (bid - 284) * 4 + sb;    // [0, 768)
        int b = bp / 12, p = bp - b * 12;
        int dow = TE[(b * 24 + p) * 2 + 0];
        int tod = TE[(b * 24 + p) * 2 + 1];
        float v = Wte1[dow * 64 + d] + Wte1[(7 + tod) * 64 + d] + bte1[d];
        hsh[sb][d] = fmaxf(v, 0.0f);
        __syncthreads();
        float acc = bte2[d];
        for (int k = 0; k < 64; k++) acc = fmaf(hsh[sb][k], Wte2[k * 64 + d], acc);
        teo[bp * 64 + d] = acc;
    }
}

// full GRU step. Wave owns cols [16w,16w+16). Gate + cand fragments streamed
// from ws (L2-resident; remat beats spill at the 128-reg budget). RS is a
// SEPARATE buffer (alias is spill-bait: R19). No soldv (R15 lesson).
__device__ __forceinline__ void gru_full(
    const u32* __restrict__ XIN, u32* __restrict__ S, u32* __restrict__ RS,
    const u16* __restrict__ frG, const u16* __restrict__ frC,
    float bgr, float bgu, float bcc, int l, int col) {
    const int n16 = l & 15, q = l >> 4;
    f32x4 accR[4], accU[4], accC[4];
    #pragma unroll
    for (int mt = 0; mt < 4; mt++) {
        accR[mt] = (f32x4)0.0f; accU[mt] = (f32x4)0.0f; accC[mt] = (f32x4)0.0f;
    }
    // phase 1: ks 0..1 (XIN K-half): one A-frag feeds R+U+C
    #pragma unroll
    for (int ks = 0; ks < 2; ks++) {
        bf16x8 gRh = ldfrag(frG + (ks * 2 + 0) * 512 + l * 8);
        bf16x8 gRl = ldfrag(frG + (ks * 2 + 1) * 512 + l * 8);
        bf16x8 gUh = ldfrag(frG + (8 + ks * 2 + 0) * 512 + l * 8);
        bf16x8 gUl = ldfrag(frG + (8 + ks * 2 + 1) * 512 + l * 8);
        bf16x8 bhiC = ldfrag(frC + (ks * 2 + 0) * 512 + l * 8);
        bf16x8 bloC = ldfrag(frC + (ks * 2 + 1) * 512 + l * 8);
        const int kk = ks * 32 + q * 8;
        #pragma unroll
        for (int mt = 0; mt < 4; mt++) {
            bf16x8 ahi, alo;
            lda_packed(XIN, mt * 16 + n16, kk, ahi, alo);
            accR[mt] = MFMA(ahi, gRh, accR[mt]);
            accR[mt] = MFMA(alo, gRh, accR[mt]);
            accR[mt] = MFMA(ahi, gRl, accR[mt]);
            accU[mt] = MFMA(ahi, gUh, accU[mt]);
            accU[mt] = MFMA(alo, gUh, accU[mt]);
            accU[mt] = MFMA(ahi, gUl, accU[mt]);
            accC[mt] = MFMA(ahi, bhiC, accC[mt]);
            accC[mt] = MFMA(alo, bhiC, accC[mt]);
            accC[mt] = MFMA(ahi, bloC, accC[mt]);
        }
    }
    // phase 2: ks 2..3 (S K-half): gates only
    #pragma unroll
    for (int ks = 2; ks < 4; ks++) {
        bf16x8 gRh = ldfrag(frG + (ks * 2 + 0) * 512 + l * 8);
        bf16x8 gRl = ldfrag(frG + (ks * 2 + 1) * 512 + l * 8);
        bf16x8 gUh = ldfrag(frG + (8 + ks * 2 + 0) * 512 + l * 8);
        bf16x8 gUl = ldfrag(frG + (8 + ks * 2 + 1) * 512 + l * 8);
        const int kk = (ks - 2) * 32 + q * 8;
        #pragma unroll
        for (int mt = 0; mt < 4; mt++) {
            bf16x8 ahi, alo;
            lda_packed(S, mt * 16 + n16, kk, ahi, alo);
            accR[mt] = MFMA(ahi, gRh, accR[mt]);
            accR[mt] = MFMA(alo, gRh, accR[mt]);
            accR[mt] = MFMA(ahi, gRl, accR[mt]);
            accU[mt] = MFMA(ahi, gUh, accU[mt]);
            accU[mt] = MFMA(alo, gUh, accU[mt]);
            accU[mt] = MFMA(ahi, gUl, accU[mt]);
        }
    }
    // rs = sigmoid(r) * s (RS separate buffer -> no barrier needed first)
    #pragma unroll
    for (int mt = 0; mt < 4; mt++)
        #pragma unroll
        for (int r = 0; r < 4; r++) {
            int tok = mt * 16 + q * 4 + r;
            int a = SW(tok, col);
            RS[a] = packf(fsigmoid(accR[mt][r] + bgr) * unpackf(S[a]));
        }
    __syncthreads();   // rs visible
    // cand ks 2..3 (RS K-half)
    #pragma unroll
    for (int ks = 2; ks < 4; ks++) {
        bf16x8 bhi = ldfrag(frC + (ks * 2 + 0) * 512 + l * 8);
        bf16x8 blo = ldfrag(frC + (ks * 2 + 1) * 512 + l * 8);
        const int kk = (ks - 2) * 32 + q * 8;
        #pragma unroll
        for (int mt = 0; mt < 4; mt++) {
            bf16x8 ahi, alo;
            lda_packed(RS, mt * 16 + n16, kk, ahi, alo);
            accC[mt] = MFMA(ahi, bhi, accC[mt]);
            accC[mt] = MFMA(alo, bhi, accC[mt]);
            accC[mt] = MFMA(ahi, blo, accC[mt]);
        }
    }
    // state update (sold re-read from LDS: same thread, same address)
    #pragma unroll
    for (int mt = 0; mt < 4; mt++)
        #pragma unroll
        for (int r = 0; r < 4; r++) {
            int tok = mt * 16 + q * 4 + r;
            int a = SW(tok, col);
            float u = fsigmoid(accU[mt][r] + bgu);
            float cnd = ftanh(accC[mt][r] + bcc);
            float sold = unpackf(S[a]);
            S[a] = packf(u * sold + (1.0f - u) * cnd);
        }
    __syncthreads();   // state visible; RS reads done
}

__global__ __launch_bounds__(256, 2) void gman_main(
    const float* __restrict__ X, const float* __restrict__ ws,
    const float* __restrict__ Win1, const float* __restrict__ bin1,
    const float* __restrict__ bg1, const float* __restrict__ bc1,
    const float* __restrict__ bg2, const float* __restrict__ bc2,
    const float* __restrict__ bo1, const float* __restrict__ Wo2,
    const float* __restrict__ bo2, float* __restrict__ out) {
    __shared__ u32 XE[4096], S1[4096], S2[4096], RS[4096];   // 64 KB
    __shared__ u32 FRX[4096];                                // +16 KB Win2 frags
    // total 80 KB; 2 blocks/CU

    const int tid = threadIdx.x;
    const int l = tid & 63;
    const int w = tid >> 6;
    const int uw = __builtin_amdgcn_readfirstlane(w);
    const int n16 = l & 15, q = l >> 4;
    const int col = uw * 16 + n16;
    const int b = blockIdx.x >> 4;
    const int nb = blockIdx.x & 15;
    const int n0 = nb << 6;

    const u16* frU = (const u16*)ws;
    const u16* frG1 = frU + uw * 8192;
    const u16* frG2 = frU + 32768 + uw * 8192;
    const u16* frC1 = frU + 65536 + uw * 4096;
    const u16* frC2 = frU + 81920 + uw * 4096;
    const u16* frH  = frU + 106496 + uw * 2048;
    const float* seQ = ws + 57344 + (((nb * 4 + uw) * 64) + l) * 16;
    const float* teo = ws + 122880;

    // stage Win2 frag table (FR_XE, dwords 49152..53247) into LDS
    const u32* frXsrc = (const u32*)ws + 49152;
    #pragma unroll
    for (int i = 0; i < 16; i++) FRX[tid + i * 256] = frXsrc[tid + i * 256];
    const u32* frXL = FRX + uw * 1024;   // per-wave quarter, dword units

    #pragma unroll
    for (int i = 0; i < 16; i++) { S1[tid + i * 256] = 0u; S2[tid + i * 256] = 0u; }

    f32x4 se_v[4];
    #pragma unroll
    for (int mt = 0; mt < 4; mt++) se_v[mt] = *(const f32x4*)(seQ + mt * 4);
    const float bg1r = bg1[col], bg1u = bg1[64 + col], bc1c = bc1[col];
    const float bg2r = bg2[col], bg2u = bg2[64 + col], bc2c = bc2[col];

    __syncthreads();   // FRX + S-init visible before first use

    #pragma unroll 1
    for (int p = 0; p < 12; p++) {
        // raw x direct from global (L1-resident row; 4 values per thread)
        const float* xrow = X + (b * 12 + p) * NB + n0;
        float xm[4];
        #pragma unroll
        for (int mt = 0; mt < 4; mt++) xm[mt] = xrow[mt * 16 + n16];
        const float tev = teo[(b * 12 + p) * 64 + col];
        // xe GEMM: A = h1 = relu(x*Win1+bin1) built in regs, B = Win2 quarter (LDS)
        f32x4 accX[4];
        #pragma unroll
        for (int mt = 0; mt < 4; mt++) accX[mt] = (f32x4)0.0f;
        #pragma unroll
        for (int ks = 0; ks < 2; ks++) {
            const int k0 = ks * 32 + q * 8;
            f32x4 w1a = *(const f32x4*)(Win1 + k0), w1b = *(const f32x4*)(Win1 + k0 + 4);
            f32x4 b1a = *(const f32x4*)(bin1 + k0), b1b = *(const f32x4*)(bin1 + k0 + 4);
            bf16x8 bhi = ldfragL(frXL + (ks * 2 + 0) * 256 + l * 4);
            bf16x8 blo = ldfragL(frXL + (ks * 2 + 1) * 256 + l * 4);
            #pragma unroll
            for (int mt = 0; mt < 4; mt++) {
                f32x4 h0, h1v;
                #pragma unroll
                for (int i = 0; i < 4; i++) {
                    h0[i]  = fmaxf(fmaf(xm[mt], w1a[i], b1a[i]), 0.0f);
                    h1v[i] = fmaxf(fmaf(xm[mt], w1b[i], b1b[i]), 0.0f);
                }
                bf16x8 ahi, alo; split8(h0, h1v, ahi, alo);
                accX[mt] = MFMA(ahi, bhi, accX[mt]);
                accX[mt] = MFMA(alo, bhi, accX[mt]);
                accX[mt] = MFMA(ahi, blo, accX[mt]);
            }
        }
        // XE write safe without pre-barrier: last XE reads (gru1 phase 1 of
        // step p-1) retired before p-1's rs barrier.
        #pragma unroll
        for (int mt = 0; mt < 4; mt++)
            #pragma unroll
            for (int r = 0; r < 4; r++) {
                int tok = mt * 16 + q * 4 + r;
                XE[SW(tok, col)] = packf(accX[mt][r] + se_v[mt][r] + tev);
            }
        __syncthreads();   // XE complete

        gru_full(XE, S1, RS, frG1, frC1, bg1r, bg1u, bc1c, l, col);
        gru_full(S1, S2, RS, frG2, frC2, bg2r, bg2u, bc2c, l, col);
    }

    // head: h = relu(S2@Wo1+bo1) via MFMA into XE (packed), then y GEMV
    f32x4 accH[4];
    #pragma unroll
    for (int mt = 0; mt < 4; mt++) accH[mt] = (f32x4)0.0f;
    #pragma unroll
    for (int ks = 0; ks < 2; ks++) {
        bf16x8 bhi = ldfrag(frH + (ks * 2 + 0) * 512 + l * 8);
        bf16x8 blo = ldfrag(frH + (ks * 2 + 1) * 512 + l * 8);
        const int kk = ks * 32 + q * 8;
        #pragma unroll
        for (int mt = 0; mt < 4; mt++) {
            bf16x8 ahi, alo;
            lda_packed(S2, mt * 16 + n16, kk, ahi, alo);
            accH[mt] = MFMA(ahi, bhi, accH[mt]);
            accH[mt] = MFMA(alo, bhi, accH[mt]);
            accH[mt] = MFMA(ahi, blo, accH[mt]);
        }
    }
    const float bo1c = bo1[col];
    #pragma unroll
    for (int mt = 0; mt < 4; mt++)
        #pragma unroll
        for (int r = 0; r < 4; r++) {
            int tok = mt * 16 + q * 4 + r;
            XE[SW(tok, col)] = packf(fmaxf(accH[mt][r] + bo1c, 0.0f));
        }
    __syncthreads();
    // y: lane = token, wave owns q-cols 3w..3w+2
    const int swzt = SWZ(l);
    float y0 = bo2[3 * uw + 0], y1 = bo2[3 * uw + 1], y2 = bo2[3 * uw + 2];
    #pragma unroll
    for (int c = 0; c < 16; c++) {
        i32x4 d = *(const i32x4*)(XE + l * 64 + c * 4);
        const int j0 = (c * 4) ^ swzt;
        #pragma unroll
        for (int e = 0; e < 4; e++) {
            float hj = unpackf((u32)d[e]);
            int j = j0 + e;
            y0 = fmaf(hj, Wo2[j * 12 + 3 * uw + 0], y0);
            y1 = fmaf(hj, Wo2[j * 12 + 3 * uw + 1], y1);
            y2 = fmaf(hj, Wo2[j * 12 + 3 * uw + 2], y2);
        }
    }
    out[(b * 12 + 3 * uw + 0) * NB + n0 + l] = y0;
    out[(b * 12 + 3 * uw + 1) * NB + n0 + l] = y1;
    out[(b * 12 + 3 * uw + 2) * NB + n0 + l] = y2;
}

extern "C" void kernel_launch(void* const* d_in, const int* in_sizes, int n_in,
                              void* d_out, int out_size, void* d_ws, size_t ws_size,
                              hipStream_t stream) {
    const float* X    = (const float*)d_in[0];
    // d_in[1]=ZC, d_in[2]=ZF unused by the reference
    const float* SE   = (const float*)d_in[3];
    const float* Wse1 = (const float*)d_in[4];
    const float* bse1 = (const float*)d_in[5];
    const float* Wse2 = (const float*)d_in[6];
    const float* bse2 = (const float*)d_in[7];
    const float* Wte1 = (const float*)d_in[8];
    const float* bte1 = (const float*)d_in[9];
    const float* Wte2 = (const float*)d_in[10];
    const float* bte2 = (const float*)d_in[11];
    const float* Win1 = (const float*)d_in[12];
    const float* bin1 = (const float*)d_in[13];
    const float* Win2 = (const float*)d_in[14];
    const float* bin2 = (const float*)d_in[15];
    const float* Wg1  = (const float*)d_in[16];
    const float* bg1  = (const float*)d_in[17];
    const float* Wc1  = (const float*)d_in[18];
    const float* bc1  = (const float*)d_in[19];
    const float* Wg2  = (const float*)d_in[20];
    const float* bg2  = (const float*)d_in[21];
    const float* Wc2  = (const float*)d_in[22];
    const float* bc2  = (const float*)d_in[23];
    const float* Wo1  = (const float*)d_in[24];
    const float* bo1  = (const float*)d_in[25];
    const float* Wo2  = (const float*)d_in[26];
    const float* bo2  = (const float*)d_in[27];
    const int*   TE   = (const int*)d_in[28];

    float* ws = (float*)d_ws;                  // 172032 floats = 688 KB
    u16* fr = (u16*)ws;
    float* seB = ws + 57344;
    float* teo = ws + 122880;
    float* out = (float*)d_out;

    prep_all<<<476, 256, 0, stream>>>(Wg1, Wg2, Wc1, Wc2, Win2, Wo1,
                                      SE, Wse1, bse1, Wse2, bse2, bin2,
                                      TE, Wte1, bte1, Wte2, bte2,
                                      fr, seB, teo);
    gman_main<<<1024, 256, 0, stream>>>(X, ws, Win1, bin1, bg1, bc1, bg2, bc2,
                                        bo1, Wo2, bo2, out);
}